// Round 4
// baseline (582.511 us; speedup 1.0000x reference)
//
#include <hip/hip_runtime.h>
#include <cmath>

#define B_   4
#define D_   1024
#define S_   1024
#define H_   16
#define DH_  64
#define DFF_ 4096

typedef __attribute__((ext_vector_type(8))) short bf16x8;  // 8 bf16 in 4 VGPRs
typedef __attribute__((ext_vector_type(4))) float f32x4;

__device__ __forceinline__ unsigned short f2b(float f) {
    unsigned int u = __float_as_uint(f);
    u += 0x7fffu + ((u >> 16) & 1u);   // RNE
    return (unsigned short)(u >> 16);
}

// async global->LDS, 16B per lane; LDS dest = wave-uniform base + lane*16
__device__ __forceinline__ void gload_lds16(const unsigned short* g, unsigned short* l) {
    __builtin_amdgcn_global_load_lds(
        (const __attribute__((address_space(1))) void*)g,
        (__attribute__((address_space(3))) void*)l, 16, 0, 0);
}

// ---------------------------------------------------------------------------
// bf16 MFMA GEMM, 128x128 tile, BK=32, 256 thr = 4 waves (2x2), wave tile
// 64x64 = 16 MFMAs/k-step. RES variant fuses: C = A@Wt^T + bias + residual,
// writes fp32 + per-block (sum,sumsq) partials for the norm that follows.
// RES requires N==1024, BM=128 (batch = 8 y-tiles, chunks = 64/batch).
// ---------------------------------------------------------------------------
template <bool RES>
__global__ __launch_bounds__(256, 2)
void gemm_bf16(const unsigned short* __restrict__ A,   // [M,K] bf16
               const unsigned short* __restrict__ Wt,  // [N,K] bf16
               const float* __restrict__ bias,
               const float* __restrict__ residual,     // RES: [M,N] fp32
               float* __restrict__ Cf, unsigned short* __restrict__ Cb,
               float* __restrict__ partial,            // RES: [B][64][2]
               int N, int K, int relu)
{
    __shared__ unsigned short As[128 * 32];
    __shared__ unsigned short Bs[128 * 32];
    const int tid = threadIdx.x;
    const int w = tid >> 6, lane = tid & 63;
    const int quad = lane >> 4, l16 = lane & 15;
    const int m0 = blockIdx.y * 128, n0 = blockIdx.x * 128;
    const int wm = (w >> 1) * 64, wn = (w & 1) * 64;
    const int srow = lane >> 2, scol = (lane & 3) * 8;  // staging lane map

    f32x4 acc[4][4] = {};

    for (int k0 = 0; k0 < K; k0 += 32) {
        gload_lds16(A + (size_t)(m0 + w * 16 + srow) * K + k0 + scol, As + w * 512);
        gload_lds16(A + (size_t)(m0 + (w + 4) * 16 + srow) * K + k0 + scol, As + (w + 4) * 512);
        gload_lds16(Wt + (size_t)(n0 + w * 16 + srow) * K + k0 + scol, Bs + w * 512);
        gload_lds16(Wt + (size_t)(n0 + (w + 4) * 16 + srow) * K + k0 + scol, Bs + (w + 4) * 512);
        __syncthreads();

        bf16x8 af[4], bfr[4];
#pragma unroll
        for (int i = 0; i < 4; ++i)
            af[i] = *(const bf16x8*)&As[(wm + i * 16 + l16) * 32 + quad * 8];
#pragma unroll
        for (int j = 0; j < 4; ++j)
            bfr[j] = *(const bf16x8*)&Bs[(wn + j * 16 + l16) * 32 + quad * 8];
#pragma unroll
        for (int i = 0; i < 4; ++i)
#pragma unroll
            for (int j = 0; j < 4; ++j)
                acc[i][j] = __builtin_amdgcn_mfma_f32_16x16x32_bf16(af[i], bfr[j], acc[i][j], 0, 0, 0);
        __syncthreads();
    }

    float s = 0.f, ss = 0.f;
#pragma unroll
    for (int i = 0; i < 4; ++i) {
        const int grow = m0 + wm + i * 16 + quad * 4;
#pragma unroll
        for (int j = 0; j < 4; ++j) {
            const int gcol = n0 + wn + j * 16 + l16;
            const float bv = bias ? bias[gcol] : 0.f;
#pragma unroll
            for (int r = 0; r < 4; ++r) {
                float vv = acc[i][j][r] + bv;
                if (relu) vv = fmaxf(vv, 0.f);
                if constexpr (RES) {
                    vv += residual[(size_t)(grow + r) * N + gcol];
                    s += vv; ss += vv * vv;
                    Cf[(size_t)(grow + r) * N + gcol] = vv;
                } else {
                    if (Cf) Cf[(size_t)(grow + r) * N + gcol] = vv;
                    if (Cb) Cb[(size_t)(grow + r) * N + gcol] = f2b(vv);
                }
            }
        }
    }

    if constexpr (RES) {
        // block-level (sum, sumsq) -> partial[b*64 + chunk]
        float* rs = (float*)As;         // LDS reuse after final barrier
        float* rss = rs + 256;
        rs[tid] = s; rss[tid] = ss;
        __syncthreads();
        for (int off = 128; off > 0; off >>= 1) {
            if (tid < off) { rs[tid] += rs[tid + off]; rss[tid] += rss[tid + off]; }
            __syncthreads();
        }
        if (tid == 0) {
            const int b = blockIdx.y >> 3;
            const int chunk = (blockIdx.y & 7) * gridDim.x + blockIdx.x;
            partial[((size_t)b * 64 + chunk) * 2 + 0] = rs[0];
            partial[((size_t)b * 64 + chunk) * 2 + 1] = rss[0];
        }
    }
}

// ---------------------------------------------------------------------------
// MFMA flash attention v2. grid (S/128, H, B), 256 thr = 4 waves. Wave w owns
// q rows {q0+16w..+16} (A) and {q0+64+16w..+16} (B). K staged [key][dh],
// V read pre-transposed vt=[b,h,dh,S] -> Vt[dh][key]. No-max softmax
// (scores bounded), l reduced once at the end. P via LDS (C->A layout).
// ---------------------------------------------------------------------------
template <bool CAUSAL>
__global__ __launch_bounds__(256, 2)
void attn_mfma2(const unsigned short* __restrict__ q, const unsigned short* __restrict__ k,
                const unsigned short* __restrict__ vt, unsigned short* __restrict__ o,
                int qstride, int kstride)
{
    __shared__ unsigned short Ks[64][72];
    __shared__ unsigned short Vt[64][72];
    __shared__ unsigned short Ps[4][2][16][72];
    const int tid = threadIdx.x;
    const int w = tid >> 6, lane = tid & 63;
    const int quad = lane >> 4, l16 = lane & 15;
    const int h = blockIdx.y, b = blockIdx.z;
    const int bx = blockIdx.x, q0 = bx * 128;

    const unsigned short* qA = q + (size_t)(b * S_ + q0 + w * 16 + l16) * qstride + h * DH_;
    const unsigned short* qB = qA + (size_t)64 * qstride;
    const bf16x8 qa0 = *(const bf16x8*)(qA + quad * 8);
    const bf16x8 qa1 = *(const bf16x8*)(qA + 32 + quad * 8);
    const bf16x8 qb0 = *(const bf16x8*)(qB + quad * 8);
    const bf16x8 qb1 = *(const bf16x8*)(qB + 32 + quad * 8);

    f32x4 OA[4] = {}, OB[4] = {};
    float lA[4] = {}, lB[4] = {};

    const int nblk = CAUSAL ? (2 * bx + 2) : (S_ / 64);
    for (int t = 0; t < nblk; ++t) {
        const int j0 = t * 64;
#pragma unroll
        for (int it = 0; it < 2; ++it) {
            const int id2 = tid + it * 256;
            const int row = id2 >> 3, c8 = (id2 & 7) * 8;
            *(bf16x8*)&Ks[row][c8] =
                *(const bf16x8*)(k + (size_t)(b * S_ + j0 + row) * kstride + h * DH_ + c8);
            *(bf16x8*)&Vt[row][c8] =
                *(const bf16x8*)(vt + (size_t)((b * H_ + h) * DH_ + row) * S_ + j0 + c8);
        }
        __syncthreads();

        const bool doA = !CAUSAL || (t <= 2 * bx);
        const bool diagA = CAUSAL && (t == 2 * bx);
        const bool diagB = CAUSAL && (t == 2 * bx + 1);

        f32x4 stA[4], stB[4];
#pragma unroll
        for (int n = 0; n < 4; ++n) {
            const bf16x8 kf0 = *(const bf16x8*)&Ks[n * 16 + l16][quad * 8];
            const bf16x8 kf1 = *(const bf16x8*)&Ks[n * 16 + l16][32 + quad * 8];
            if (doA) {
                f32x4 c = {};
                c = __builtin_amdgcn_mfma_f32_16x16x32_bf16(qa0, kf0, c, 0, 0, 0);
                c = __builtin_amdgcn_mfma_f32_16x16x32_bf16(qa1, kf1, c, 0, 0, 0);
                stA[n] = c;
            }
            f32x4 c = {};
            c = __builtin_amdgcn_mfma_f32_16x16x32_bf16(qb0, kf0, c, 0, 0, 0);
            c = __builtin_amdgcn_mfma_f32_16x16x32_bf16(qb1, kf1, c, 0, 0, 0);
            stB[n] = c;
        }

        if (doA) {
#pragma unroll
            for (int n = 0; n < 4; ++n)
#pragma unroll
                for (int r = 0; r < 4; ++r) {
                    float sv = stA[n][r] * 0.125f;
                    if (diagA) {
                        const int row = q0 + w * 16 + quad * 4 + r;
                        const int key = j0 + n * 16 + l16;
                        if (key > row) sv = -1e30f;
                    }
                    const float p = __expf(sv);
                    lA[r] += p;
                    Ps[w][0][quad * 4 + r][n * 16 + l16] = f2b(p);
                }
        }
#pragma unroll
        for (int n = 0; n < 4; ++n)
#pragma unroll
            for (int r = 0; r < 4; ++r) {
                float sv = stB[n][r] * 0.125f;
                if (diagB) {
                    const int row = q0 + 64 + w * 16 + quad * 4 + r;
                    const int key = j0 + n * 16 + l16;
                    if (key > row) sv = -1e30f;
                }
                const float p = __expf(sv);
                lB[r] += p;
                Ps[w][1][quad * 4 + r][n * 16 + l16] = f2b(p);
            }
        __threadfence_block();

        const bf16x8 pa0 = *(const bf16x8*)&Ps[w][0][l16][quad * 8];
        const bf16x8 pa1 = *(const bf16x8*)&Ps[w][0][l16][32 + quad * 8];
        const bf16x8 pb0 = *(const bf16x8*)&Ps[w][1][l16][quad * 8];
        const bf16x8 pb1 = *(const bf16x8*)&Ps[w][1][l16][32 + quad * 8];
#pragma unroll
        for (int n = 0; n < 4; ++n) {
            const bf16x8 vf0 = *(const bf16x8*)&Vt[n * 16 + l16][quad * 8];
            const bf16x8 vf1 = *(const bf16x8*)&Vt[n * 16 + l16][32 + quad * 8];
            if (doA) {
                OA[n] = __builtin_amdgcn_mfma_f32_16x16x32_bf16(pa0, vf0, OA[n], 0, 0, 0);
                OA[n] = __builtin_amdgcn_mfma_f32_16x16x32_bf16(pa1, vf1, OA[n], 0, 0, 0);
            }
            OB[n] = __builtin_amdgcn_mfma_f32_16x16x32_bf16(pb0, vf0, OB[n], 0, 0, 0);
            OB[n] = __builtin_amdgcn_mfma_f32_16x16x32_bf16(pb1, vf1, OB[n], 0, 0, 0);
        }
        __syncthreads();
    }

#pragma unroll
    for (int r = 0; r < 4; ++r) {
        float la = lA[r], lb = lB[r];
        la += __shfl_xor(la, 1); la += __shfl_xor(la, 2);
        la += __shfl_xor(la, 4); la += __shfl_xor(la, 8);
        lb += __shfl_xor(lb, 1); lb += __shfl_xor(lb, 2);
        lb += __shfl_xor(lb, 4); lb += __shfl_xor(lb, 8);
        const float ia = 1.f / la, ib = 1.f / lb;
        const size_t baseA = (size_t)(b * S_ + q0 + w * 16 + quad * 4 + r) * D_ + h * DH_;
        const size_t baseB = baseA + (size_t)64 * D_;
#pragma unroll
        for (int n = 0; n < 4; ++n) {
            o[baseA + n * 16 + l16] = f2b(OA[n][r] * ia);
            o[baseB + n * 16 + l16] = f2b(OB[n][r] * ib);
        }
    }
}

// ---------------------------------------------------------------------------
// u16 transpose for V: per (b,h) -> dst[((b*H+h)*64+dh)*S + s].
// grid (S/32, 2, B*H), block (32,8).
// ---------------------------------------------------------------------------
__global__ void transpose_v(const unsigned short* __restrict__ src,
                            unsigned short* __restrict__ dst, int istride)
{
    __shared__ unsigned short t[32][34];
    const int z = blockIdx.z, b = z >> 4, h = z & 15;
    const int s0 = blockIdx.x * 32, d0 = blockIdx.y * 32;
    const int tx = threadIdx.x, ty = threadIdx.y;
#pragma unroll
    for (int i = 0; i < 4; ++i)
        t[ty + i * 8][tx] =
            src[(size_t)(b * S_ + s0 + ty + i * 8) * istride + h * DH_ + d0 + tx];
    __syncthreads();
#pragma unroll
    for (int i = 0; i < 4; ++i)
        dst[(size_t)(z * DH_ + d0 + ty + i * 8) * S_ + s0 + tx] = t[tx][ty + i * 8];
}

// ---------------------------------------------------------------------------
// 8 square (1024x1024) weight transposes fused: dst + z*1M <- src[z]^T (bf16)
// ---------------------------------------------------------------------------
struct SrcPack { const float* p[8]; };

__global__ void wtrans8(SrcPack pk, unsigned short* __restrict__ dst)
{
    __shared__ float tile[32][33];
    const int z = blockIdx.z;
    const float* src = pk.p[z];
    const int c0 = blockIdx.x * 32, r0 = blockIdx.y * 32;
    const int tx = threadIdx.x, ty = threadIdx.y;
#pragma unroll
    for (int i = 0; i < 4; ++i)
        tile[ty + i * 8][tx] = src[(size_t)(r0 + ty + i * 8) * 1024 + c0 + tx];
    __syncthreads();
#pragma unroll
    for (int i = 0; i < 4; ++i)
        dst[(size_t)z * 1048576 + (size_t)(c0 + ty + i * 8) * 1024 + r0 + tx] =
            f2b(tile[tx][ty + i * 8]);
}

// reduce partials (chunks per batch) -> stats[b] = {mean, 1/(||x-mean||+eps)}
__global__ void norm_finalize(const float* __restrict__ partial,
                              float* __restrict__ stats, int chunks)
{
    const int b = blockIdx.x;
    float s = 0.f, ss = 0.f;
    for (int i = threadIdx.x; i < chunks; i += 256) {
        s  += partial[((size_t)b * chunks + i) * 2 + 0];
        ss += partial[((size_t)b * chunks + i) * 2 + 1];
    }
    __shared__ float rs[256], rss[256];
    rs[threadIdx.x] = s; rss[threadIdx.x] = ss;
    __syncthreads();
    for (int off = 128; off > 0; off >>= 1) {
        if (threadIdx.x < off) {
            rs[threadIdx.x] += rs[threadIdx.x + off];
            rss[threadIdx.x] += rss[threadIdx.x + off];
        }
        __syncthreads();
    }
    if (threadIdx.x == 0) {
        const float size = (float)(D_ * S_);
        float mean = rs[0] / size;
        float var = fmaxf(rss[0] - size * mean * mean, 0.f);
        stats[b * 2 + 0] = mean;
        stats[b * 2 + 1] = 1.f / (sqrtf(var) + 1e-7f);
    }
}

// in-place normalize y (fp32) + write bf16 copy. grid (64, B).
__global__ void norm_apply_dual(float* __restrict__ y, unsigned short* __restrict__ yb,
                                const float* __restrict__ stats)
{
    const int perBatch = D_ * S_;
    const int b = blockIdx.y;
    const float mean = stats[b * 2 + 0], inv = stats[b * 2 + 1];
    float4* y4 = (float4*)(y + (size_t)b * perBatch);
    unsigned short* yb_ = yb + (size_t)b * perBatch;
    const int n4 = perBatch / 4;
    for (int i = blockIdx.x * blockDim.x + threadIdx.x; i < n4;
         i += gridDim.x * blockDim.x) {
        float4 v = y4[i];
        v.x = (v.x - mean) * inv; v.y = (v.y - mean) * inv;
        v.z = (v.z - mean) * inv; v.w = (v.w - mean) * inv;
        y4[i] = v;
        ushort4 hh; hh.x = f2b(v.x); hh.y = f2b(v.y); hh.z = f2b(v.z); hh.w = f2b(v.w);
        *(ushort4*)(yb_ + (size_t)i * 4) = hh;
    }
}

// ---------------------------------------------------------------------------
// Per-batch fp32 transpose [z,R,C] -> [z,C,R]; optional fp32 out, bf16 out,
// stats normalization. block (32,8), grid (C/32, R/32, Z).
// ---------------------------------------------------------------------------
__global__ void transpose_dual(const float* __restrict__ in, float* __restrict__ outf,
                               unsigned short* __restrict__ outb, int R, int C,
                               const float* __restrict__ stats)
{
    __shared__ float tile[32][33];
    const int z = blockIdx.z;
    const float* ip = in + (size_t)z * R * C;
    const int c0 = blockIdx.x * 32, r0 = blockIdx.y * 32;
    const int tx = threadIdx.x, ty = threadIdx.y;

    float mean = 0.f, inv = 1.f;
    if (stats) { mean = stats[z * 2 + 0]; inv = stats[z * 2 + 1]; }

#pragma unroll
    for (int i = 0; i < 4; ++i)
        tile[ty + i * 8][tx] = ip[(size_t)(r0 + ty + i * 8) * C + c0 + tx];
    __syncthreads();
#pragma unroll
    for (int i = 0; i < 4; ++i) {
        const float v = (tile[tx][ty + i * 8] - mean) * inv;
        const size_t oidx = (size_t)z * R * C + (size_t)(c0 + ty + i * 8) * R + r0 + tx;
        if (outf) outf[oidx] = v;
        if (outb) outb[oidx] = f2b(v);
    }
}

// ---------------------------------------------------------------------------
extern "C" void kernel_launch(void* const* d_in, const int* in_sizes, int n_in,
                              void* d_out, int out_size, void* d_ws, size_t ws_size,
                              hipStream_t stream)
{
    const float* embedding = (const float*)d_in[0];
    const float* other     = (const float*)d_in[1];
    const float* W1 = (const float*)d_in[10];
    const float* b1 = (const float*)d_in[11];
    const float* W2 = (const float*)d_in[12];
    const float* b2 = (const float*)d_in[13];
    float* out = (float*)d_out;

    char* wsb = (char*)d_ws;
    const size_t MB = 1u << 20;
    float* f0 = (float*)(wsb + 0 * MB);    // xT fp32, later pe
    float* f2 = (float*)(wsb + 32 * MB);   // pa / final raw
    unsigned short* wts  = (unsigned short*)(wsb + 48 * MB);  // bf16 weights
    unsigned short* wqkv = wts;                       // [3072,1024]
    unsigned short* wo_s = wts + 3 * 1048576;
    unsigned short* wq_c = wts + 4 * 1048576;
    unsigned short* wkv_c= wts + 5 * 1048576;         // [2048,1024]
    unsigned short* wo_c = wts + 7 * 1048576;
    unsigned short* w1t  = wts + 8 * 1048576;         // [4096,1024]
    unsigned short* w2t  = wts + 12 * 1048576;        // [1024,4096]
    unsigned short* actA = (unsigned short*)(wsb + 80 * MB);  // 4M bf16
    unsigned short* actB = (unsigned short*)(wsb + 88 * MB);  // 4M bf16
    unsigned short* actC = (unsigned short*)(wsb + 96 * MB);  // big scratch
    unsigned short* actC2 = actC + 4 * 1048576;
    float* partial = (float*)(wsb + 130 * MB);
    float* stats   = partial + 2048;

    const dim3 blkT(32, 8), blk256(256);
    const dim3 gT(32, 32, B_);
    const dim3 gAttn(S_ / 128, H_, B_);
    const dim3 gVt(32, 2, B_ * H_);
    const dim3 gApply(64, B_);
    const dim3 gG1024(8, 32);   // N=1024 gemm

    // ---- weight prep ----
    SrcPack pk;
    pk.p[0] = (const float*)d_in[2]; pk.p[1] = (const float*)d_in[3];
    pk.p[2] = (const float*)d_in[4]; pk.p[3] = (const float*)d_in[5];
    pk.p[4] = (const float*)d_in[6]; pk.p[5] = (const float*)d_in[7];
    pk.p[6] = (const float*)d_in[8]; pk.p[7] = (const float*)d_in[9];
    hipLaunchKernelGGL(wtrans8, dim3(32, 32, 8), blkT, 0, stream, pk, wts);
    hipLaunchKernelGGL(transpose_dual, dim3(128, 32, 1), blkT, 0, stream, W1, nullptr, w1t, 1024, 4096, nullptr);
    hipLaunchKernelGGL(transpose_dual, dim3(32, 128, 1), blkT, 0, stream, W2, nullptr, w2t, 4096, 1024, nullptr);

    // ---- xT (fp32 f0 + bf16 actA) ----
    hipLaunchKernelGGL(transpose_dual, gT, blkT, 0, stream, other, f0, actA, D_, S_, nullptr);

    // ---- self attention ----
    hipLaunchKernelGGL(gemm_bf16<false>, dim3(24, 32), blk256, 0, stream,
                       actA, wqkv, nullptr, nullptr, nullptr, actC, nullptr, 3072, 1024, 0);
    hipLaunchKernelGGL(transpose_v, gVt, blkT, 0, stream, actC + 2048, actA, 3072);
    hipLaunchKernelGGL(attn_mfma2<true>, gAttn, blk256, 0, stream,
                       actC, actC + 1024, actA, actB, 3072, 3072);
    // pa_raw = attn@Wo_s + xT : fused residual + partials -> f2
    hipLaunchKernelGGL(gemm_bf16<true>, gG1024, blk256, 0, stream,
                       actB, wo_s, nullptr, f0, f2, nullptr, partial, 1024, 1024, 0);
    hipLaunchKernelGGL(norm_finalize, dim3(B_), blk256, 0, stream, partial, stats, 64);
    hipLaunchKernelGGL(norm_apply_dual, gApply, blk256, 0, stream, f2, actA, stats);

    // ---- cross attention ----
    hipLaunchKernelGGL(transpose_dual, gT, blkT, 0, stream, embedding, nullptr, actB, D_, S_, nullptr);
    hipLaunchKernelGGL(gemm_bf16<false>, gG1024, blk256, 0, stream,
                       actA, wq_c, nullptr, nullptr, nullptr, actC, nullptr, 1024, 1024, 0);
    hipLaunchKernelGGL(gemm_bf16<false>, dim3(16, 32), blk256, 0, stream,
                       actB, wkv_c, nullptr, nullptr, nullptr, actC2, nullptr, 2048, 1024, 0);
    hipLaunchKernelGGL(transpose_v, gVt, blkT, 0, stream, actC2 + 1024, actB, 2048);
    hipLaunchKernelGGL(attn_mfma2<false>, gAttn, blk256, 0, stream,
                       actC, actC2, actB, actA, 1024, 2048);
    // pe_raw = ca@Wo_c + pa : fused -> f0
    hipLaunchKernelGGL(gemm_bf16<true>, gG1024, blk256, 0, stream,
                       actA, wo_c, nullptr, f2, f0, nullptr, partial, 1024, 1024, 0);
    hipLaunchKernelGGL(norm_finalize, dim3(B_), blk256, 0, stream, partial, stats, 64);
    hipLaunchKernelGGL(norm_apply_dual, gApply, blk256, 0, stream, f0, actA, stats);

    // ---- MLP ----
    hipLaunchKernelGGL(gemm_bf16<false>, dim3(32, 32), blk256, 0, stream,
                       actA, w1t, b1, nullptr, nullptr, actC, nullptr, DFF_, 1024, 1);
    // final_raw = h1@W2 + b2 + pe : fused -> f2
    hipLaunchKernelGGL(gemm_bf16<true>, gG1024, blk256, 0, stream,
                       actC, w2t, b2, f0, f2, nullptr, partial, 1024, DFF_, 0);
    hipLaunchKernelGGL(norm_finalize, dim3(B_), blk256, 0, stream, partial, stats, 64);
    hipLaunchKernelGGL(transpose_dual, gT, blkT, 0, stream, f2, out, nullptr, S_, D_, stats);

    (void)in_sizes; (void)n_in; (void)out_size; (void)ws_size;
}

// Round 5
// 547.638 us; speedup vs baseline: 1.0637x; 1.0637x over previous
//
#include <hip/hip_runtime.h>
#include <cmath>

#define B_   4
#define D_   1024
#define S_   1024
#define H_   16
#define DH_  64
#define DFF_ 4096

typedef __attribute__((ext_vector_type(8))) short bf16x8;  // 8 bf16 in 4 VGPRs
typedef __attribute__((ext_vector_type(4))) float f32x4;

__device__ __forceinline__ unsigned short f2b(float f) {
    unsigned int u = __float_as_uint(f);
    u += 0x7fffu + ((u >> 16) & 1u);   // RNE
    return (unsigned short)(u >> 16);
}

// async global->LDS, 16B per lane; LDS dest = wave-uniform base + lane*16
__device__ __forceinline__ void gload_lds16(const unsigned short* g, unsigned short* l) {
    __builtin_amdgcn_global_load_lds(
        (const __attribute__((address_space(1))) void*)g,
        (__attribute__((address_space(3))) void*)l, 16, 0, 0);
}

// ---------------------------------------------------------------------------
// bf16 MFMA GEMM, BMxBN tile, BK=32, 256 thr = 4 waves in 2x2, wave tile
// (BM/2)x(BN/2). Supports K-split via blockIdx.z (A,Wt advance by z*K cols,
// Cf by z*csplit). RES fuses bias+residual+fp32-out+(sum,sumsq) partials.
// Grid sizing rule: keep >= 512 blocks (>=2 blocks/CU) for latency hiding.
// ---------------------------------------------------------------------------
template <int BM, int BN, bool RES>
__global__ __launch_bounds__(256, 2)
void gemm_t(const unsigned short* __restrict__ A,   // [M,lda] bf16
            const unsigned short* __restrict__ Wt,  // [N,ldb] bf16
            const float* __restrict__ bias,
            const float* __restrict__ residual,     // RES: [M,N] fp32
            float* __restrict__ Cf, unsigned short* __restrict__ Cb,
            float* __restrict__ partial,            // RES: [B][chunks][2]
            int N, int K, int lda, int ldb, long csplit, int relu)
{
    constexpr int FM = BM / 32, FN = BN / 32;  // frags per wave
    __shared__ unsigned short As[BM * 32];
    __shared__ unsigned short Bs[BN * 32];
    const int tid = threadIdx.x;
    const int w = tid >> 6, lane = tid & 63;
    const int quad = lane >> 4, l16 = lane & 15;
    const int m0 = blockIdx.y * BM, n0 = blockIdx.x * BN;
    const int wm = (w >> 1) * (BM / 2), wn = (w & 1) * (BN / 2);
    const int srow = lane >> 2, scol = (lane & 3) * 8;

    A  += (size_t)blockIdx.z * K;
    Wt += (size_t)blockIdx.z * K;
    if (Cf) Cf += (size_t)blockIdx.z * csplit;

    f32x4 acc[FM][FN] = {};

    for (int k0 = 0; k0 < K; k0 += 32) {
#pragma unroll
        for (int i = 0; i < BM / 64; ++i)
            gload_lds16(A + (size_t)(m0 + (w + 4 * i) * 16 + srow) * lda + k0 + scol,
                        As + (w + 4 * i) * 512);
#pragma unroll
        for (int i = 0; i < BN / 64; ++i)
            gload_lds16(Wt + (size_t)(n0 + (w + 4 * i) * 16 + srow) * ldb + k0 + scol,
                        Bs + (w + 4 * i) * 512);
        __syncthreads();

        bf16x8 af[FM], bfr[FN];
#pragma unroll
        for (int i = 0; i < FM; ++i)
            af[i] = *(const bf16x8*)&As[(wm + i * 16 + l16) * 32 + quad * 8];
#pragma unroll
        for (int j = 0; j < FN; ++j)
            bfr[j] = *(const bf16x8*)&Bs[(wn + j * 16 + l16) * 32 + quad * 8];
#pragma unroll
        for (int i = 0; i < FM; ++i)
#pragma unroll
            for (int j = 0; j < FN; ++j)
                acc[i][j] = __builtin_amdgcn_mfma_f32_16x16x32_bf16(af[i], bfr[j], acc[i][j], 0, 0, 0);
        __syncthreads();
    }

    float s = 0.f, ss = 0.f;
#pragma unroll
    for (int i = 0; i < FM; ++i) {
        const int grow = m0 + wm + i * 16 + quad * 4;
#pragma unroll
        for (int j = 0; j < FN; ++j) {
            const int gcol = n0 + wn + j * 16 + l16;
            const float bv = bias ? bias[gcol] : 0.f;
#pragma unroll
            for (int r = 0; r < 4; ++r) {
                float vv = acc[i][j][r] + bv;
                if (relu) vv = fmaxf(vv, 0.f);
                if constexpr (RES) {
                    vv += residual[(size_t)(grow + r) * N + gcol];
                    s += vv; ss += vv * vv;
                    Cf[(size_t)(grow + r) * N + gcol] = vv;
                } else {
                    if (Cf) Cf[(size_t)(grow + r) * N + gcol] = vv;
                    if (Cb) Cb[(size_t)(grow + r) * N + gcol] = f2b(vv);
                }
            }
        }
    }

    if constexpr (RES) {
        float* rs = (float*)As;          // LDS reuse after final barrier
        float* rss = rs + 256;
        rs[tid] = s; rss[tid] = ss;
        __syncthreads();
        for (int off = 128; off > 0; off >>= 1) {
            if (tid < off) { rs[tid] += rs[tid + off]; rss[tid] += rss[tid + off]; }
            __syncthreads();
        }
        if (tid == 0) {
            constexpr int YPB = S_ / BM;                 // y-blocks per batch
            const int b = blockIdx.y / YPB;
            const int chunk = (blockIdx.y % YPB) * gridDim.x + blockIdx.x;
            const int chunks = YPB * gridDim.x;
            partial[((size_t)b * chunks + chunk) * 2 + 0] = rs[0];
            partial[((size_t)b * chunks + chunk) * 2 + 1] = rss[0];
        }
    }
}

// ---------------------------------------------------------------------------
// y = pc0+pc1+pc2+pc3 + bias[col] + res, with (sum,sumsq) partials.
// grid (64, B), 256 thr. chunks = 64.
// ---------------------------------------------------------------------------
__global__ void reduce4_res(const float* __restrict__ pc, const float* __restrict__ res,
                            const float* __restrict__ bias, float* __restrict__ y,
                            float* __restrict__ partial)
{
    const size_t pcs = (size_t)4096 * 1024;
    const int b = blockIdx.y;
    const size_t base = (size_t)b * 1048576 + (size_t)blockIdx.x * 16384;
    float s = 0.f, ss = 0.f;
    for (int i = threadIdx.x; i < 4096; i += 256) {
        const size_t e = base + (size_t)i * 4;
        float4 v0 = *(const float4*)&pc[e];
        float4 v1 = *(const float4*)&pc[e + pcs];
        float4 v2 = *(const float4*)&pc[e + 2 * pcs];
        float4 v3 = *(const float4*)&pc[e + 3 * pcs];
        float4 rv = *(const float4*)&res[e];
        float4 bv = *(const float4*)&bias[e & 1023];
        float4 o;
        o.x = v0.x + v1.x + v2.x + v3.x + rv.x + bv.x;
        o.y = v0.y + v1.y + v2.y + v3.y + rv.y + bv.y;
        o.z = v0.z + v1.z + v2.z + v3.z + rv.z + bv.z;
        o.w = v0.w + v1.w + v2.w + v3.w + rv.w + bv.w;
        *(float4*)&y[e] = o;
        s += o.x + o.y + o.z + o.w;
        ss += o.x * o.x + o.y * o.y + o.z * o.z + o.w * o.w;
    }
    __shared__ float rs[256], rss[256];
    rs[threadIdx.x] = s; rss[threadIdx.x] = ss;
    __syncthreads();
    for (int off = 128; off > 0; off >>= 1) {
        if (threadIdx.x < off) {
            rs[threadIdx.x] += rs[threadIdx.x + off];
            rss[threadIdx.x] += rss[threadIdx.x + off];
        }
        __syncthreads();
    }
    if (threadIdx.x == 0) {
        partial[((size_t)b * 64 + blockIdx.x) * 2 + 0] = rs[0];
        partial[((size_t)b * 64 + blockIdx.x) * 2 + 1] = rss[0];
    }
}

// stats from partial: {mean, 1/(||x-mean||+eps)} computed in-block
__device__ __forceinline__ void stats_reduce(const float* __restrict__ partial,
                                             int b, int chunks, int tid,
                                             float* rs, float* rss,
                                             float& mean, float& inv)
{
    float s = 0.f, ss = 0.f;
    for (int i = tid; i < chunks; i += 256) {
        s  += partial[((size_t)b * chunks + i) * 2 + 0];
        ss += partial[((size_t)b * chunks + i) * 2 + 1];
    }
    rs[tid] = s; rss[tid] = ss;
    __syncthreads();
    for (int off = 128; off > 0; off >>= 1) {
        if (tid < off) { rs[tid] += rs[tid + off]; rss[tid] += rss[tid + off]; }
        __syncthreads();
    }
    const float size = (float)(D_ * S_);
    const float m = rs[0] / size;
    const float var = fmaxf(rss[0] - size * m * m, 0.f);
    mean = m;
    inv = 1.f / (sqrtf(var) + 1e-7f);
    __syncthreads();
}

// in-place normalize y (fp32) + write bf16 copy; stats inline. grid (64, B).
__global__ void norm_apply_dual(float* __restrict__ y, unsigned short* __restrict__ yb,
                                const float* __restrict__ partial, int chunks)
{
    __shared__ float rs[256], rss[256];
    const int b = blockIdx.y;
    float mean, inv;
    stats_reduce(partial, b, chunks, threadIdx.x, rs, rss, mean, inv);

    const int perBatch = D_ * S_;
    float4* y4 = (float4*)(y + (size_t)b * perBatch);
    unsigned short* yb_ = yb + (size_t)b * perBatch;
    const int n4 = perBatch / 4;
    for (int i = blockIdx.x * blockDim.x + threadIdx.x; i < n4;
         i += gridDim.x * blockDim.x) {
        float4 v = y4[i];
        v.x = (v.x - mean) * inv; v.y = (v.y - mean) * inv;
        v.z = (v.z - mean) * inv; v.w = (v.w - mean) * inv;
        y4[i] = v;
        ushort4 hh; hh.x = f2b(v.x); hh.y = f2b(v.y); hh.z = f2b(v.z); hh.w = f2b(v.w);
        *(ushort4*)(yb_ + (size_t)i * 4) = hh;
    }
}

// ---------------------------------------------------------------------------
// MFMA flash attention v2. grid (S/128, H, B), 256 thr = 4 waves. Wave w owns
// q rows {q0+16w..+16} (A) and {q0+64+16w..+16} (B). K staged [key][dh],
// V read pre-transposed vt=[b,h,dh,S] -> Vt[dh][key]. No-max softmax
// (scores bounded), l reduced once at the end. P via LDS (C->A layout).
// ---------------------------------------------------------------------------
template <bool CAUSAL>
__global__ __launch_bounds__(256, 2)
void attn_mfma2(const unsigned short* __restrict__ q, const unsigned short* __restrict__ k,
                const unsigned short* __restrict__ vt, unsigned short* __restrict__ o,
                int qstride, int kstride)
{
    __shared__ unsigned short Ks[64][72];
    __shared__ unsigned short Vt[64][72];
    __shared__ unsigned short Ps[4][2][16][72];
    const int tid = threadIdx.x;
    const int w = tid >> 6, lane = tid & 63;
    const int quad = lane >> 4, l16 = lane & 15;
    const int h = blockIdx.y, b = blockIdx.z;
    const int bx = blockIdx.x, q0 = bx * 128;

    const unsigned short* qA = q + (size_t)(b * S_ + q0 + w * 16 + l16) * qstride + h * DH_;
    const unsigned short* qB = qA + (size_t)64 * qstride;
    const bf16x8 qa0 = *(const bf16x8*)(qA + quad * 8);
    const bf16x8 qa1 = *(const bf16x8*)(qA + 32 + quad * 8);
    const bf16x8 qb0 = *(const bf16x8*)(qB + quad * 8);
    const bf16x8 qb1 = *(const bf16x8*)(qB + 32 + quad * 8);

    f32x4 OA[4] = {}, OB[4] = {};
    float lA[4] = {}, lB[4] = {};

    const int nblk = CAUSAL ? (2 * bx + 2) : (S_ / 64);
    for (int t = 0; t < nblk; ++t) {
        const int j0 = t * 64;
#pragma unroll
        for (int it = 0; it < 2; ++it) {
            const int id2 = tid + it * 256;
            const int row = id2 >> 3, c8 = (id2 & 7) * 8;
            *(bf16x8*)&Ks[row][c8] =
                *(const bf16x8*)(k + (size_t)(b * S_ + j0 + row) * kstride + h * DH_ + c8);
            *(bf16x8*)&Vt[row][c8] =
                *(const bf16x8*)(vt + (size_t)((b * H_ + h) * DH_ + row) * S_ + j0 + c8);
        }
        __syncthreads();

        const bool doA = !CAUSAL || (t <= 2 * bx);
        const bool diagA = CAUSAL && (t == 2 * bx);
        const bool diagB = CAUSAL && (t == 2 * bx + 1);

        f32x4 stA[4], stB[4];
#pragma unroll
        for (int n = 0; n < 4; ++n) {
            const bf16x8 kf0 = *(const bf16x8*)&Ks[n * 16 + l16][quad * 8];
            const bf16x8 kf1 = *(const bf16x8*)&Ks[n * 16 + l16][32 + quad * 8];
            if (doA) {
                f32x4 c = {};
                c = __builtin_amdgcn_mfma_f32_16x16x32_bf16(qa0, kf0, c, 0, 0, 0);
                c = __builtin_amdgcn_mfma_f32_16x16x32_bf16(qa1, kf1, c, 0, 0, 0);
                stA[n] = c;
            }
            f32x4 c = {};
            c = __builtin_amdgcn_mfma_f32_16x16x32_bf16(qb0, kf0, c, 0, 0, 0);
            c = __builtin_amdgcn_mfma_f32_16x16x32_bf16(qb1, kf1, c, 0, 0, 0);
            stB[n] = c;
        }

        if (doA) {
#pragma unroll
            for (int n = 0; n < 4; ++n)
#pragma unroll
                for (int r = 0; r < 4; ++r) {
                    float sv = stA[n][r] * 0.125f;
                    if (diagA) {
                        const int row = q0 + w * 16 + quad * 4 + r;
                        const int key = j0 + n * 16 + l16;
                        if (key > row) sv = -1e30f;
                    }
                    const float p = __expf(sv);
                    lA[r] += p;
                    Ps[w][0][quad * 4 + r][n * 16 + l16] = f2b(p);
                }
        }
#pragma unroll
        for (int n = 0; n < 4; ++n)
#pragma unroll
            for (int r = 0; r < 4; ++r) {
                float sv = stB[n][r] * 0.125f;
                if (diagB) {
                    const int row = q0 + 64 + w * 16 + quad * 4 + r;
                    const int key = j0 + n * 16 + l16;
                    if (key > row) sv = -1e30f;
                }
                const float p = __expf(sv);
                lB[r] += p;
                Ps[w][1][quad * 4 + r][n * 16 + l16] = f2b(p);
            }
        __threadfence_block();

        const bf16x8 pa0 = *(const bf16x8*)&Ps[w][0][l16][quad * 8];
        const bf16x8 pa1 = *(const bf16x8*)&Ps[w][0][l16][32 + quad * 8];
        const bf16x8 pb0 = *(const bf16x8*)&Ps[w][1][l16][quad * 8];
        const bf16x8 pb1 = *(const bf16x8*)&Ps[w][1][l16][32 + quad * 8];
#pragma unroll
        for (int n = 0; n < 4; ++n) {
            const bf16x8 vf0 = *(const bf16x8*)&Vt[n * 16 + l16][quad * 8];
            const bf16x8 vf1 = *(const bf16x8*)&Vt[n * 16 + l16][32 + quad * 8];
            if (doA) {
                OA[n] = __builtin_amdgcn_mfma_f32_16x16x32_bf16(pa0, vf0, OA[n], 0, 0, 0);
                OA[n] = __builtin_amdgcn_mfma_f32_16x16x32_bf16(pa1, vf1, OA[n], 0, 0, 0);
            }
            OB[n] = __builtin_amdgcn_mfma_f32_16x16x32_bf16(pb0, vf0, OB[n], 0, 0, 0);
            OB[n] = __builtin_amdgcn_mfma_f32_16x16x32_bf16(pb1, vf1, OB[n], 0, 0, 0);
        }
        __syncthreads();
    }

#pragma unroll
    for (int r = 0; r < 4; ++r) {
        float la = lA[r], lb = lB[r];
        la += __shfl_xor(la, 1); la += __shfl_xor(la, 2);
        la += __shfl_xor(la, 4); la += __shfl_xor(la, 8);
        lb += __shfl_xor(lb, 1); lb += __shfl_xor(lb, 2);
        lb += __shfl_xor(lb, 4); lb += __shfl_xor(lb, 8);
        const float ia = 1.f / la, ib = 1.f / lb;
        const size_t baseA = (size_t)(b * S_ + q0 + w * 16 + quad * 4 + r) * D_ + h * DH_;
        const size_t baseB = baseA + (size_t)64 * D_;
#pragma unroll
        for (int n = 0; n < 4; ++n) {
            o[baseA + n * 16 + l16] = f2b(OA[n][r] * ia);
            o[baseB + n * 16 + l16] = f2b(OB[n][r] * ib);
        }
    }
}

// ---------------------------------------------------------------------------
// u16 transpose for V: per (b,h) -> dst[((b*H+h)*64+dh)*S + s].
// grid (S/32, 2, B*H), block (32,8).
// ---------------------------------------------------------------------------
__global__ void transpose_v(const unsigned short* __restrict__ src,
                            unsigned short* __restrict__ dst, int istride)
{
    __shared__ unsigned short t[32][34];
    const int z = blockIdx.z, b = z >> 4, h = z & 15;
    const int s0 = blockIdx.x * 32, d0 = blockIdx.y * 32;
    const int tx = threadIdx.x, ty = threadIdx.y;
#pragma unroll
    for (int i = 0; i < 4; ++i)
        t[ty + i * 8][tx] =
            src[(size_t)(b * S_ + s0 + ty + i * 8) * istride + h * DH_ + d0 + tx];
    __syncthreads();
#pragma unroll
    for (int i = 0; i < 4; ++i)
        dst[(size_t)(z * DH_ + d0 + ty + i * 8) * S_ + s0 + tx] = t[tx][ty + i * 8];
}

// ---------------------------------------------------------------------------
// 8 square (1024x1024) weight transposes fused: dst + z*1M <- src[z]^T (bf16)
// ---------------------------------------------------------------------------
struct SrcPack { const float* p[8]; };

__global__ void wtrans8(SrcPack pk, unsigned short* __restrict__ dst)
{
    __shared__ float tile[32][33];
    const int z = blockIdx.z;
    const float* src = pk.p[z];
    const int c0 = blockIdx.x * 32, r0 = blockIdx.y * 32;
    const int tx = threadIdx.x, ty = threadIdx.y;
#pragma unroll
    for (int i = 0; i < 4; ++i)
        tile[ty + i * 8][tx] = src[(size_t)(r0 + ty + i * 8) * 1024 + c0 + tx];
    __syncthreads();
#pragma unroll
    for (int i = 0; i < 4; ++i)
        dst[(size_t)z * 1048576 + (size_t)(c0 + ty + i * 8) * 1024 + r0 + tx] =
            f2b(tile[tx][ty + i * 8]);
}

// ---------------------------------------------------------------------------
// Per-batch fp32 transpose [z,R,C] -> [z,C,R]; optional fp32/bf16 out;
// optional normalization with stats inline-reduced from partial.
// block (32,8), grid (C/32, R/32, Z).
// ---------------------------------------------------------------------------
__global__ void transpose_dual(const float* __restrict__ in, float* __restrict__ outf,
                               unsigned short* __restrict__ outb, int R, int C,
                               const float* __restrict__ partial, int chunks)
{
    __shared__ float tile[32][33];
    __shared__ float rs[256], rss[256];
    const int z = blockIdx.z;
    const int tx = threadIdx.x, ty = threadIdx.y;
    const int tid = ty * 32 + tx;

    float mean = 0.f, inv = 1.f;
    if (partial) {
        float s = 0.f, ss = 0.f;
        for (int i = tid; i < chunks; i += 256) {
            s  += partial[((size_t)z * chunks + i) * 2 + 0];
            ss += partial[((size_t)z * chunks + i) * 2 + 1];
        }
        rs[tid] = s; rss[tid] = ss;
        __syncthreads();
        for (int off = 128; off > 0; off >>= 1) {
            if (tid < off) { rs[tid] += rs[tid + off]; rss[tid] += rss[tid + off]; }
            __syncthreads();
        }
        const float size = (float)(D_ * S_);
        mean = rs[0] / size;
        const float var = fmaxf(rss[0] - size * mean * mean, 0.f);
        inv = 1.f / (sqrtf(var) + 1e-7f);
        __syncthreads();
    }

    const float* ip = in + (size_t)z * R * C;
    const int c0 = blockIdx.x * 32, r0 = blockIdx.y * 32;
#pragma unroll
    for (int i = 0; i < 4; ++i)
        tile[ty + i * 8][tx] = ip[(size_t)(r0 + ty + i * 8) * C + c0 + tx];
    __syncthreads();
#pragma unroll
    for (int i = 0; i < 4; ++i) {
        const float v = (tile[tx][ty + i * 8] - mean) * inv;
        const size_t oidx = (size_t)z * R * C + (size_t)(c0 + ty + i * 8) * R + r0 + tx;
        if (outf) outf[oidx] = v;
        if (outb) outb[oidx] = f2b(v);
    }
}

// ---------------------------------------------------------------------------
extern "C" void kernel_launch(void* const* d_in, const int* in_sizes, int n_in,
                              void* d_out, int out_size, void* d_ws, size_t ws_size,
                              hipStream_t stream)
{
    const float* embedding = (const float*)d_in[0];
    const float* other     = (const float*)d_in[1];
    const float* W1 = (const float*)d_in[10];
    const float* b1 = (const float*)d_in[11];
    const float* W2 = (const float*)d_in[12];
    const float* b2 = (const float*)d_in[13];
    float* out = (float*)d_out;

    char* wsb = (char*)d_ws;
    const size_t MB = 1u << 20;
    float* f0 = (float*)(wsb + 0 * MB);    // xT fp32 -> pe fp32
    float* f2 = (float*)(wsb + 16 * MB);   // pa fp32 -> final raw
    unsigned short* wts  = (unsigned short*)(wsb + 32 * MB);  // bf16 weights 32MB
    unsigned short* wqkv = wts;                       // [3072,1024]
    unsigned short* wo_s = wts + 3 * 1048576;
    unsigned short* wq_c = wts + 4 * 1048576;
    unsigned short* wkv_c= wts + 5 * 1048576;         // [2048,1024]
    unsigned short* wo_c = wts + 7 * 1048576;
    unsigned short* w1t  = wts + 8 * 1048576;         // [4096,1024]
    unsigned short* w2t  = wts + 12 * 1048576;        // [1024,4096]
    unsigned short* actA = (unsigned short*)(wsb + 64 * MB);  // 8MB
    unsigned short* actB = (unsigned short*)(wsb + 72 * MB);  // 8MB
    unsigned short* actC = (unsigned short*)(wsb + 80 * MB);  // 32MB (qkv/h1)
    unsigned short* actC2 = actC + 4 * 1048576;
    float* pc      = (float*)(wsb + 112 * MB);        // 64MB: 4 K-split partials
    float* partial = (float*)(wsb + 176 * MB);

    const dim3 blkT(32, 8), blk256(256);
    const dim3 gT(32, 32, B_);
    const dim3 gAttn(S_ / 128, H_, B_);
    const dim3 gVt(32, 2, B_ * H_);
    const dim3 gApply(64, B_);

    // ---- weight prep ----
    SrcPack pk;
    pk.p[0] = (const float*)d_in[2]; pk.p[1] = (const float*)d_in[3];
    pk.p[2] = (const float*)d_in[4]; pk.p[3] = (const float*)d_in[5];
    pk.p[4] = (const float*)d_in[6]; pk.p[5] = (const float*)d_in[7];
    pk.p[6] = (const float*)d_in[8]; pk.p[7] = (const float*)d_in[9];
    hipLaunchKernelGGL(wtrans8, dim3(32, 32, 8), blkT, 0, stream, pk, wts);
    hipLaunchKernelGGL(transpose_dual, dim3(128, 32, 1), blkT, 0, stream, W1, nullptr, w1t, 1024, 4096, nullptr, 0);
    hipLaunchKernelGGL(transpose_dual, dim3(32, 128, 1), blkT, 0, stream, W2, nullptr, w2t, 4096, 1024, nullptr, 0);

    // ---- xT (fp32 f0 + bf16 actA) ----
    hipLaunchKernelGGL(transpose_dual, gT, blkT, 0, stream, other, f0, actA, D_, S_, nullptr, 0);

    // ---- self attention ----
    hipLaunchKernelGGL((gemm_t<128, 128, false>), dim3(24, 32), blk256, 0, stream,
                       actA, wqkv, nullptr, nullptr, nullptr, actC, nullptr,
                       3072, 1024, 1024, 1024, 0L, 0);
    hipLaunchKernelGGL(transpose_v, gVt, blkT, 0, stream, actC + 2048, actA, 3072);
    hipLaunchKernelGGL(attn_mfma2<true>, gAttn, blk256, 0, stream,
                       actC, actC + 1024, actA, actB, 3072, 3072);
    // pa_raw = attn@Wo_s + xT -> f2 (+partials, chunks=128)
    hipLaunchKernelGGL((gemm_t<64, 128, true>), dim3(8, 64), blk256, 0, stream,
                       actB, wo_s, nullptr, f0, f2, nullptr, partial,
                       1024, 1024, 1024, 1024, 0L, 0);
    hipLaunchKernelGGL(norm_apply_dual, gApply, blk256, 0, stream, f2, actA, partial, 128);

    // ---- cross attention ----
    hipLaunchKernelGGL(transpose_dual, gT, blkT, 0, stream, embedding, nullptr, actB, D_, S_, nullptr, 0);
    hipLaunchKernelGGL((gemm_t<64, 128, false>), dim3(8, 64), blk256, 0, stream,
                       actA, wq_c, nullptr, nullptr, nullptr, actC, nullptr,
                       1024, 1024, 1024, 1024, 0L, 0);
    hipLaunchKernelGGL((gemm_t<128, 128, false>), dim3(16, 32), blk256, 0, stream,
                       actB, wkv_c, nullptr, nullptr, nullptr, actC2, nullptr,
                       2048, 1024, 1024, 1024, 0L, 0);
    hipLaunchKernelGGL(transpose_v, gVt, blkT, 0, stream, actC2 + 1024, actB, 2048);
    hipLaunchKernelGGL(attn_mfma2<false>, gAttn, blk256, 0, stream,
                       actC, actC2, actB, actA, 1024, 2048);
    // pe_raw = ca@Wo_c + pa -> f0 (+partials)
    hipLaunchKernelGGL((gemm_t<64, 128, true>), dim3(8, 64), blk256, 0, stream,
                       actA, wo_c, nullptr, f2, f0, nullptr, partial,
                       1024, 1024, 1024, 1024, 0L, 0);
    hipLaunchKernelGGL(norm_apply_dual, gApply, blk256, 0, stream, f0, actA, partial, 128);

    // ---- MLP ----
    hipLaunchKernelGGL((gemm_t<128, 128, false>), dim3(32, 32), blk256, 0, stream,
                       actA, w1t, b1, nullptr, nullptr, actC, nullptr,
                       DFF_, 1024, 1024, 1024, 0L, 1);
    // W2 K-split x4: pc[z] = h1[:, z*1024:(z+1)*1024] @ W2t[:, z*1024:...]^T
    hipLaunchKernelGGL((gemm_t<128, 128, false>), dim3(8, 32, 4), blk256, 0, stream,
                       actC, w2t, nullptr, nullptr, pc, nullptr, nullptr,
                       1024, 1024, 4096, 4096, (long)4096 * 1024, 0);
    // final_raw = sum(pc) + b2 + pe -> f2 (+partials, chunks=64)
    hipLaunchKernelGGL(reduce4_res, gApply, blk256, 0, stream, pc, f0, b2, f2, partial);
    hipLaunchKernelGGL(transpose_dual, gT, blkT, 0, stream, f2, out, nullptr, S_, D_, partial, 64);

    (void)in_sizes; (void)n_in; (void)out_size; (void)ws_size;
}

// Round 6
// 534.981 us; speedup vs baseline: 1.0888x; 1.0237x over previous
//
#include <hip/hip_runtime.h>
#include <cmath>

#define B_   4
#define D_   1024
#define S_   1024
#define H_   16
#define DH_  64
#define DFF_ 4096

typedef __attribute__((ext_vector_type(8))) short bf16x8;  // 8 bf16 in 4 VGPRs
typedef __attribute__((ext_vector_type(4))) float f32x4;

__device__ __forceinline__ unsigned short f2b(float f) {
    unsigned int u = __float_as_uint(f);
    u += 0x7fffu + ((u >> 16) & 1u);   // RNE
    return (unsigned short)(u >> 16);
}

// async global->LDS, 16B per lane; LDS dest = wave-uniform base + lane*16
__device__ __forceinline__ void gload_lds16(const unsigned short* g, unsigned short* l) {
    __builtin_amdgcn_global_load_lds(
        (const __attribute__((address_space(1))) void*)g,
        (__attribute__((address_space(3))) void*)l, 16, 0, 0);
}

// ---------------------------------------------------------------------------
// bf16 MFMA GEMM, BMxBN tile, BK=32, 256 thr = 4 waves in 2x2, wave tile
// (BM/2)x(BN/2). GRID IS (Mtiles, Ntiles, ksplit): x indexes M so that the
// round-robin XCD assignment (linear%8, x fastest, Mtiles%8==0) clusters all
// blocks sharing an A row-tile onto one XCD -> A fetched ~once per XCD.
// K-split via blockIdx.z (A,Wt advance z*K cols; Cf by z*csplit).
// RES fuses bias+residual+fp32-out+(sum,sumsq) partials for the next norm.
// ---------------------------------------------------------------------------
template <int BM, int BN, bool RES>
__global__ __launch_bounds__(256, 2)
void gemm_t(const unsigned short* __restrict__ A,   // [M,lda] bf16
            const unsigned short* __restrict__ Wt,  // [N,ldb] bf16
            const float* __restrict__ bias,
            const float* __restrict__ residual,     // RES: [M,N] fp32
            float* __restrict__ Cf, unsigned short* __restrict__ Cb,
            float* __restrict__ partial,            // RES: [B][chunks][2]
            int N, int K, int lda, int ldb, long csplit, int relu)
{
    constexpr int FM = BM / 32, FN = BN / 32;  // frags per wave
    __shared__ unsigned short As[BM * 32];
    __shared__ unsigned short Bs[BN * 32];
    const int tid = threadIdx.x;
    const int w = tid >> 6, lane = tid & 63;
    const int quad = lane >> 4, l16 = lane & 15;
    const int m0 = blockIdx.x * BM, n0 = blockIdx.y * BN;   // x = M-tile!
    const int wm = (w >> 1) * (BM / 2), wn = (w & 1) * (BN / 2);
    const int srow = lane >> 2, scol = (lane & 3) * 8;

    A  += (size_t)blockIdx.z * K;
    Wt += (size_t)blockIdx.z * K;
    if (Cf) Cf += (size_t)blockIdx.z * csplit;

    f32x4 acc[FM][FN] = {};

    for (int k0 = 0; k0 < K; k0 += 32) {
#pragma unroll
        for (int i = 0; i < BM / 64; ++i)
            gload_lds16(A + (size_t)(m0 + (w + 4 * i) * 16 + srow) * lda + k0 + scol,
                        As + (w + 4 * i) * 512);
#pragma unroll
        for (int i = 0; i < BN / 64; ++i)
            gload_lds16(Wt + (size_t)(n0 + (w + 4 * i) * 16 + srow) * ldb + k0 + scol,
                        Bs + (w + 4 * i) * 512);
        __syncthreads();

        bf16x8 af[FM], bfr[FN];
#pragma unroll
        for (int i = 0; i < FM; ++i)
            af[i] = *(const bf16x8*)&As[(wm + i * 16 + l16) * 32 + quad * 8];
#pragma unroll
        for (int j = 0; j < FN; ++j)
            bfr[j] = *(const bf16x8*)&Bs[(wn + j * 16 + l16) * 32 + quad * 8];
#pragma unroll
        for (int i = 0; i < FM; ++i)
#pragma unroll
            for (int j = 0; j < FN; ++j)
                acc[i][j] = __builtin_amdgcn_mfma_f32_16x16x32_bf16(af[i], bfr[j], acc[i][j], 0, 0, 0);
        __syncthreads();
    }

    float s = 0.f, ss = 0.f;
#pragma unroll
    for (int i = 0; i < FM; ++i) {
        const int grow = m0 + wm + i * 16 + quad * 4;
#pragma unroll
        for (int j = 0; j < FN; ++j) {
            const int gcol = n0 + wn + j * 16 + l16;
            const float bv = bias ? bias[gcol] : 0.f;
#pragma unroll
            for (int r = 0; r < 4; ++r) {
                float vv = acc[i][j][r] + bv;
                if (relu) vv = fmaxf(vv, 0.f);
                if constexpr (RES) {
                    vv += residual[(size_t)(grow + r) * N + gcol];
                    s += vv; ss += vv * vv;
                    Cf[(size_t)(grow + r) * N + gcol] = vv;
                } else {
                    if (Cf) Cf[(size_t)(grow + r) * N + gcol] = vv;
                    if (Cb) Cb[(size_t)(grow + r) * N + gcol] = f2b(vv);
                }
            }
        }
    }

    if constexpr (RES) {
        float* rs = (float*)As;          // LDS reuse after final barrier
        float* rss = rs + 256;
        rs[tid] = s; rss[tid] = ss;
        __syncthreads();
        for (int off = 128; off > 0; off >>= 1) {
            if (tid < off) { rs[tid] += rs[tid + off]; rss[tid] += rss[tid + off]; }
            __syncthreads();
        }
        if (tid == 0) {
            constexpr int YPB = S_ / BM;                 // m-blocks per batch
            const int b = blockIdx.x / YPB;
            const int chunk = (blockIdx.x % YPB) * gridDim.y + blockIdx.y;
            const int chunks = YPB * gridDim.y;
            partial[((size_t)b * chunks + chunk) * 2 + 0] = rs[0];
            partial[((size_t)b * chunks + chunk) * 2 + 1] = rss[0];
        }
    }
}

// ---------------------------------------------------------------------------
// y = pc0+pc1 + bias[col] + res, with (sum,sumsq) partials. grid (64, B).
// ---------------------------------------------------------------------------
__global__ void reduce2_res(const float* __restrict__ pc, const float* __restrict__ res,
                            const float* __restrict__ bias, float* __restrict__ y,
                            float* __restrict__ partial)
{
    const size_t pcs = (size_t)4096 * 1024;
    const int b = blockIdx.y;
    const size_t base = (size_t)b * 1048576 + (size_t)blockIdx.x * 16384;
    float s = 0.f, ss = 0.f;
    for (int i = threadIdx.x; i < 4096; i += 256) {
        const size_t e = base + (size_t)i * 4;
        float4 v0 = *(const float4*)&pc[e];
        float4 v1 = *(const float4*)&pc[e + pcs];
        float4 rv = *(const float4*)&res[e];
        float4 bv = *(const float4*)&bias[e & 1023];
        float4 o;
        o.x = v0.x + v1.x + rv.x + bv.x;
        o.y = v0.y + v1.y + rv.y + bv.y;
        o.z = v0.z + v1.z + rv.z + bv.z;
        o.w = v0.w + v1.w + rv.w + bv.w;
        *(float4*)&y[e] = o;
        s += o.x + o.y + o.z + o.w;
        ss += o.x * o.x + o.y * o.y + o.z * o.z + o.w * o.w;
    }
    __shared__ float rs[256], rss[256];
    rs[threadIdx.x] = s; rss[threadIdx.x] = ss;
    __syncthreads();
    for (int off = 128; off > 0; off >>= 1) {
        if (threadIdx.x < off) {
            rs[threadIdx.x] += rs[threadIdx.x + off];
            rss[threadIdx.x] += rss[threadIdx.x + off];
        }
        __syncthreads();
    }
    if (threadIdx.x == 0) {
        partial[((size_t)b * 64 + blockIdx.x) * 2 + 0] = rs[0];
        partial[((size_t)b * 64 + blockIdx.x) * 2 + 1] = rss[0];
    }
}

// stats from partial: {mean, 1/(||x-mean||+eps)} computed in-block
__device__ __forceinline__ void stats_reduce(const float* __restrict__ partial,
                                             int b, int chunks, int tid,
                                             float* rs, float* rss,
                                             float& mean, float& inv)
{
    float s = 0.f, ss = 0.f;
    for (int i = tid; i < chunks; i += 256) {
        s  += partial[((size_t)b * chunks + i) * 2 + 0];
        ss += partial[((size_t)b * chunks + i) * 2 + 1];
    }
    rs[tid] = s; rss[tid] = ss;
    __syncthreads();
    for (int off = 128; off > 0; off >>= 1) {
        if (tid < off) { rs[tid] += rs[tid + off]; rss[tid] += rss[tid + off]; }
        __syncthreads();
    }
    const float size = (float)(D_ * S_);
    const float m = rs[0] / size;
    const float var = fmaxf(rss[0] - size * m * m, 0.f);
    mean = m;
    inv = 1.f / (sqrtf(var) + 1e-7f);
    __syncthreads();
}

// in-place normalize y (fp32) + write bf16 copy; stats inline. grid (64, B).
__global__ void norm_apply_dual(float* __restrict__ y, unsigned short* __restrict__ yb,
                                const float* __restrict__ partial, int chunks)
{
    __shared__ float rs[256], rss[256];
    const int b = blockIdx.y;
    float mean, inv;
    stats_reduce(partial, b, chunks, threadIdx.x, rs, rss, mean, inv);

    const int perBatch = D_ * S_;
    float4* y4 = (float4*)(y + (size_t)b * perBatch);
    unsigned short* yb_ = yb + (size_t)b * perBatch;
    const int n4 = perBatch / 4;
    for (int i = blockIdx.x * blockDim.x + threadIdx.x; i < n4;
         i += gridDim.x * blockDim.x) {
        float4 v = y4[i];
        v.x = (v.x - mean) * inv; v.y = (v.y - mean) * inv;
        v.z = (v.z - mean) * inv; v.w = (v.w - mean) * inv;
        y4[i] = v;
        ushort4 hh; hh.x = f2b(v.x); hh.y = f2b(v.y); hh.z = f2b(v.z); hh.w = f2b(v.w);
        *(ushort4*)(yb_ + (size_t)i * 4) = hh;
    }
}

// ---------------------------------------------------------------------------
// MFMA flash attention v2. grid (S/128, H, B), 256 thr = 4 waves. The q-tile
// is swizzled: qt = (bx + h) & 7, so each XCD (= bx%8 under round-robin) gets
// an even mix of light/heavy causal diagonals. Wave w owns q rows
// {q0+16w..+16} (A) and {q0+64+16w..+16} (B). K staged [key][dh], V read
// pre-transposed vt=[b,h,dh,S] -> Vt[dh][key]. No-max softmax (scores
// bounded), l reduced once at the end. P via LDS (C->A layout).
// ---------------------------------------------------------------------------
template <bool CAUSAL>
__global__ __launch_bounds__(256, 2)
void attn_mfma2(const unsigned short* __restrict__ q, const unsigned short* __restrict__ k,
                const unsigned short* __restrict__ vt, unsigned short* __restrict__ o,
                int qstride, int kstride)
{
    __shared__ unsigned short Ks[64][72];
    __shared__ unsigned short Vt[64][72];
    __shared__ unsigned short Ps[4][2][16][72];
    const int tid = threadIdx.x;
    const int w = tid >> 6, lane = tid & 63;
    const int quad = lane >> 4, l16 = lane & 15;
    const int h = blockIdx.y, b = blockIdx.z;
    const int qt = CAUSAL ? ((blockIdx.x + h) & 7) : blockIdx.x;
    const int q0 = qt * 128;

    const unsigned short* qA = q + (size_t)(b * S_ + q0 + w * 16 + l16) * qstride + h * DH_;
    const unsigned short* qB = qA + (size_t)64 * qstride;
    const bf16x8 qa0 = *(const bf16x8*)(qA + quad * 8);
    const bf16x8 qa1 = *(const bf16x8*)(qA + 32 + quad * 8);
    const bf16x8 qb0 = *(const bf16x8*)(qB + quad * 8);
    const bf16x8 qb1 = *(const bf16x8*)(qB + 32 + quad * 8);

    f32x4 OA[4] = {}, OB[4] = {};
    float lA[4] = {}, lB[4] = {};

    const int nblk = CAUSAL ? (2 * qt + 2) : (S_ / 64);
    for (int t = 0; t < nblk; ++t) {
        const int j0 = t * 64;
#pragma unroll
        for (int it = 0; it < 2; ++it) {
            const int id2 = tid + it * 256;
            const int row = id2 >> 3, c8 = (id2 & 7) * 8;
            *(bf16x8*)&Ks[row][c8] =
                *(const bf16x8*)(k + (size_t)(b * S_ + j0 + row) * kstride + h * DH_ + c8);
            *(bf16x8*)&Vt[row][c8] =
                *(const bf16x8*)(vt + (size_t)((b * H_ + h) * DH_ + row) * S_ + j0 + c8);
        }
        __syncthreads();

        const bool doA = !CAUSAL || (t <= 2 * qt);
        const bool diagA = CAUSAL && (t == 2 * qt);
        const bool diagB = CAUSAL && (t == 2 * qt + 1);

        f32x4 stA[4], stB[4];
#pragma unroll
        for (int n = 0; n < 4; ++n) {
            const bf16x8 kf0 = *(const bf16x8*)&Ks[n * 16 + l16][quad * 8];
            const bf16x8 kf1 = *(const bf16x8*)&Ks[n * 16 + l16][32 + quad * 8];
            if (doA) {
                f32x4 c = {};
                c = __builtin_amdgcn_mfma_f32_16x16x32_bf16(qa0, kf0, c, 0, 0, 0);
                c = __builtin_amdgcn_mfma_f32_16x16x32_bf16(qa1, kf1, c, 0, 0, 0);
                stA[n] = c;
            }
            f32x4 c = {};
            c = __builtin_amdgcn_mfma_f32_16x16x32_bf16(qb0, kf0, c, 0, 0, 0);
            c = __builtin_amdgcn_mfma_f32_16x16x32_bf16(qb1, kf1, c, 0, 0, 0);
            stB[n] = c;
        }

        if (doA) {
#pragma unroll
            for (int n = 0; n < 4; ++n)
#pragma unroll
                for (int r = 0; r < 4; ++r) {
                    float sv = stA[n][r] * 0.125f;
                    if (diagA) {
                        const int row = q0 + w * 16 + quad * 4 + r;
                        const int key = j0 + n * 16 + l16;
                        if (key > row) sv = -1e30f;
                    }
                    const float p = __expf(sv);
                    lA[r] += p;
                    Ps[w][0][quad * 4 + r][n * 16 + l16] = f2b(p);
                }
        }
#pragma unroll
        for (int n = 0; n < 4; ++n)
#pragma unroll
            for (int r = 0; r < 4; ++r) {
                float sv = stB[n][r] * 0.125f;
                if (diagB) {
                    const int row = q0 + 64 + w * 16 + quad * 4 + r;
                    const int key = j0 + n * 16 + l16;
                    if (key > row) sv = -1e30f;
                }
                const float p = __expf(sv);
                lB[r] += p;
                Ps[w][1][quad * 4 + r][n * 16 + l16] = f2b(p);
            }
        __threadfence_block();

        const bf16x8 pa0 = *(const bf16x8*)&Ps[w][0][l16][quad * 8];
        const bf16x8 pa1 = *(const bf16x8*)&Ps[w][0][l16][32 + quad * 8];
        const bf16x8 pb0 = *(const bf16x8*)&Ps[w][1][l16][quad * 8];
        const bf16x8 pb1 = *(const bf16x8*)&Ps[w][1][l16][32 + quad * 8];
#pragma unroll
        for (int n = 0; n < 4; ++n) {
            const bf16x8 vf0 = *(const bf16x8*)&Vt[n * 16 + l16][quad * 8];
            const bf16x8 vf1 = *(const bf16x8*)&Vt[n * 16 + l16][32 + quad * 8];
            if (doA) {
                OA[n] = __builtin_amdgcn_mfma_f32_16x16x32_bf16(pa0, vf0, OA[n], 0, 0, 0);
                OA[n] = __builtin_amdgcn_mfma_f32_16x16x32_bf16(pa1, vf1, OA[n], 0, 0, 0);
            }
            OB[n] = __builtin_amdgcn_mfma_f32_16x16x32_bf16(pb0, vf0, OB[n], 0, 0, 0);
            OB[n] = __builtin_amdgcn_mfma_f32_16x16x32_bf16(pb1, vf1, OB[n], 0, 0, 0);
        }
        __syncthreads();
    }

#pragma unroll
    for (int r = 0; r < 4; ++r) {
        float la = lA[r], lb = lB[r];
        la += __shfl_xor(la, 1); la += __shfl_xor(la, 2);
        la += __shfl_xor(la, 4); la += __shfl_xor(la, 8);
        lb += __shfl_xor(lb, 1); lb += __shfl_xor(lb, 2);
        lb += __shfl_xor(lb, 4); lb += __shfl_xor(lb, 8);
        const float ia = 1.f / la, ib = 1.f / lb;
        const size_t baseA = (size_t)(b * S_ + q0 + w * 16 + quad * 4 + r) * D_ + h * DH_;
        const size_t baseB = baseA + (size_t)64 * D_;
#pragma unroll
        for (int n = 0; n < 4; ++n) {
            o[baseA + n * 16 + l16] = f2b(OA[n][r] * ia);
            o[baseB + n * 16 + l16] = f2b(OB[n][r] * ib);
        }
    }
}

// ---------------------------------------------------------------------------
// u16 transpose for V: per (b,h) -> dst[((b*H+h)*64+dh)*S + s].
// grid (S/32, 2, B*H), block (32,8).
// ---------------------------------------------------------------------------
__global__ void transpose_v(const unsigned short* __restrict__ src,
                            unsigned short* __restrict__ dst, int istride)
{
    __shared__ unsigned short t[32][34];
    const int z = blockIdx.z, b = z >> 4, h = z & 15;
    const int s0 = blockIdx.x * 32, d0 = blockIdx.y * 32;
    const int tx = threadIdx.x, ty = threadIdx.y;
#pragma unroll
    for (int i = 0; i < 4; ++i)
        t[ty + i * 8][tx] =
            src[(size_t)(b * S_ + s0 + ty + i * 8) * istride + h * DH_ + d0 + tx];
    __syncthreads();
#pragma unroll
    for (int i = 0; i < 4; ++i)
        dst[(size_t)(z * DH_ + d0 + ty + i * 8) * S_ + s0 + tx] = t[tx][ty + i * 8];
}

// ---------------------------------------------------------------------------
// 8 square (1024x1024) weight transposes fused: dst + z*1M <- src[z]^T (bf16)
// ---------------------------------------------------------------------------
struct SrcPack { const float* p[8]; };

__global__ void wtrans8(SrcPack pk, unsigned short* __restrict__ dst)
{
    __shared__ float tile[32][33];
    const int z = blockIdx.z;
    const float* src = pk.p[z];
    const int c0 = blockIdx.x * 32, r0 = blockIdx.y * 32;
    const int tx = threadIdx.x, ty = threadIdx.y;
#pragma unroll
    for (int i = 0; i < 4; ++i)
        tile[ty + i * 8][tx] = src[(size_t)(r0 + ty + i * 8) * 1024 + c0 + tx];
    __syncthreads();
#pragma unroll
    for (int i = 0; i < 4; ++i)
        dst[(size_t)z * 1048576 + (size_t)(c0 + ty + i * 8) * 1024 + r0 + tx] =
            f2b(tile[tx][ty + i * 8]);
}

// ---------------------------------------------------------------------------
// Per-batch fp32 transpose [z,R,C] -> [z,C,R]; optional fp32/bf16 out;
// optional normalization with stats inline-reduced from partial.
// block (32,8), grid (C/32, R/32, Z).
// ---------------------------------------------------------------------------
__global__ void transpose_dual(const float* __restrict__ in, float* __restrict__ outf,
                               unsigned short* __restrict__ outb, int R, int C,
                               const float* __restrict__ partial, int chunks)
{
    __shared__ float tile[32][33];
    __shared__ float rs[256], rss[256];
    const int z = blockIdx.z;
    const int tx = threadIdx.x, ty = threadIdx.y;
    const int tid = ty * 32 + tx;

    float mean = 0.f, inv = 1.f;
    if (partial) {
        float s = 0.f, ss = 0.f;
        for (int i = tid; i < chunks; i += 256) {
            s  += partial[((size_t)z * chunks + i) * 2 + 0];
            ss += partial[((size_t)z * chunks + i) * 2 + 1];
        }
        rs[tid] = s; rss[tid] = ss;
        __syncthreads();
        for (int off = 128; off > 0; off >>= 1) {
            if (tid < off) { rs[tid] += rs[tid + off]; rss[tid] += rss[tid + off]; }
            __syncthreads();
        }
        const float size = (float)(D_ * S_);
        mean = rs[0] / size;
        const float var = fmaxf(rss[0] - size * mean * mean, 0.f);
        inv = 1.f / (sqrtf(var) + 1e-7f);
        __syncthreads();
    }

    const float* ip = in + (size_t)z * R * C;
    const int c0 = blockIdx.x * 32, r0 = blockIdx.y * 32;
#pragma unroll
    for (int i = 0; i < 4; ++i)
        tile[ty + i * 8][tx] = ip[(size_t)(r0 + ty + i * 8) * C + c0 + tx];
    __syncthreads();
#pragma unroll
    for (int i = 0; i < 4; ++i) {
        const float v = (tile[tx][ty + i * 8] - mean) * inv;
        const size_t oidx = (size_t)z * R * C + (size_t)(c0 + ty + i * 8) * R + r0 + tx;
        if (outf) outf[oidx] = v;
        if (outb) outb[oidx] = f2b(v);
    }
}

// ---------------------------------------------------------------------------
extern "C" void kernel_launch(void* const* d_in, const int* in_sizes, int n_in,
                              void* d_out, int out_size, void* d_ws, size_t ws_size,
                              hipStream_t stream)
{
    const float* embedding = (const float*)d_in[0];
    const float* other     = (const float*)d_in[1];
    const float* W1 = (const float*)d_in[10];
    const float* b1 = (const float*)d_in[11];
    const float* W2 = (const float*)d_in[12];
    const float* b2 = (const float*)d_in[13];
    float* out = (float*)d_out;

    char* wsb = (char*)d_ws;
    const size_t MB = 1u << 20;
    float* f0 = (float*)(wsb + 0 * MB);    // xT fp32 -> pe fp32
    float* f2 = (float*)(wsb + 16 * MB);   // pa fp32 -> final raw
    unsigned short* wts  = (unsigned short*)(wsb + 32 * MB);  // bf16 weights 32MB
    unsigned short* wqkv = wts;                       // [3072,1024]
    unsigned short* wo_s = wts + 3 * 1048576;
    unsigned short* wq_c = wts + 4 * 1048576;
    unsigned short* wkv_c= wts + 5 * 1048576;         // [2048,1024]
    unsigned short* wo_c = wts + 7 * 1048576;
    unsigned short* w1t  = wts + 8 * 1048576;         // [4096,1024]
    unsigned short* w2t  = wts + 12 * 1048576;        // [1024,4096]
    unsigned short* actA = (unsigned short*)(wsb + 64 * MB);  // 8MB
    unsigned short* actB = (unsigned short*)(wsb + 72 * MB);  // 8MB
    unsigned short* actC = (unsigned short*)(wsb + 80 * MB);  // 32MB (qkv/h1)
    unsigned short* actC2 = actC + 4 * 1048576;
    float* pc      = (float*)(wsb + 112 * MB);        // 32MB: 2 K-split partials
    float* partial = (float*)(wsb + 176 * MB);

    const dim3 blkT(32, 8), blk256(256);
    const dim3 gT(32, 32, B_);
    const dim3 gAttn(S_ / 128, H_, B_);
    const dim3 gVt(32, 2, B_ * H_);
    const dim3 gApply(64, B_);

    // ---- weight prep ----
    SrcPack pk;
    pk.p[0] = (const float*)d_in[2]; pk.p[1] = (const float*)d_in[3];
    pk.p[2] = (const float*)d_in[4]; pk.p[3] = (const float*)d_in[5];
    pk.p[4] = (const float*)d_in[6]; pk.p[5] = (const float*)d_in[7];
    pk.p[6] = (const float*)d_in[8]; pk.p[7] = (const float*)d_in[9];
    hipLaunchKernelGGL(wtrans8, dim3(32, 32, 8), blkT, 0, stream, pk, wts);
    hipLaunchKernelGGL(transpose_dual, dim3(128, 32, 1), blkT, 0, stream, W1, nullptr, w1t, 1024, 4096, nullptr, 0);
    hipLaunchKernelGGL(transpose_dual, dim3(32, 128, 1), blkT, 0, stream, W2, nullptr, w2t, 4096, 1024, nullptr, 0);

    // ---- xT (fp32 f0 + bf16 actA) ----
    hipLaunchKernelGGL(transpose_dual, gT, blkT, 0, stream, other, f0, actA, D_, S_, nullptr, 0);

    // ---- self attention ----
    hipLaunchKernelGGL((gemm_t<128, 128, false>), dim3(32, 24), blk256, 0, stream,
                       actA, wqkv, nullptr, nullptr, nullptr, actC, nullptr,
                       3072, 1024, 1024, 1024, 0L, 0);
    hipLaunchKernelGGL(transpose_v, gVt, blkT, 0, stream, actC + 2048, actA, 3072);
    hipLaunchKernelGGL(attn_mfma2<true>, gAttn, blk256, 0, stream,
                       actC, actC + 1024, actA, actB, 3072, 3072);
    // pa_raw = attn@Wo_s + xT -> f2 (+partials, chunks=128)
    hipLaunchKernelGGL((gemm_t<64, 128, true>), dim3(64, 8), blk256, 0, stream,
                       actB, wo_s, nullptr, f0, f2, nullptr, partial,
                       1024, 1024, 1024, 1024, 0L, 0);
    hipLaunchKernelGGL(norm_apply_dual, gApply, blk256, 0, stream, f2, actA, partial, 128);

    // ---- cross attention ----
    hipLaunchKernelGGL(transpose_dual, gT, blkT, 0, stream, embedding, nullptr, actB, D_, S_, nullptr, 0);
    hipLaunchKernelGGL((gemm_t<64, 128, false>), dim3(64, 8), blk256, 0, stream,
                       actA, wq_c, nullptr, nullptr, nullptr, actC, nullptr,
                       1024, 1024, 1024, 1024, 0L, 0);
    hipLaunchKernelGGL((gemm_t<128, 128, false>), dim3(32, 16), blk256, 0, stream,
                       actB, wkv_c, nullptr, nullptr, nullptr, actC2, nullptr,
                       2048, 1024, 1024, 1024, 0L, 0);
    hipLaunchKernelGGL(transpose_v, gVt, blkT, 0, stream, actC2 + 1024, actB, 2048);
    hipLaunchKernelGGL(attn_mfma2<false>, gAttn, blk256, 0, stream,
                       actC, actC2, actB, actA, 1024, 2048);
    // pe_raw = ca@Wo_c + pa -> f0 (+partials)
    hipLaunchKernelGGL((gemm_t<64, 128, true>), dim3(64, 8), blk256, 0, stream,
                       actA, wo_c, nullptr, f2, f0, nullptr, partial,
                       1024, 1024, 1024, 1024, 0L, 0);
    hipLaunchKernelGGL(norm_apply_dual, gApply, blk256, 0, stream, f0, actA, partial, 128);

    // ---- MLP ----
    hipLaunchKernelGGL((gemm_t<128, 128, false>), dim3(32, 32), blk256, 0, stream,
                       actA, w1t, b1, nullptr, nullptr, actC, nullptr,
                       DFF_, 1024, 1024, 1024, 0L, 1);
    // W2 K-split x2: pc[z] = h1[:, z*2048:(z+1)*2048] @ W2t[:, z*2048:...]^T
    hipLaunchKernelGGL((gemm_t<128, 128, false>), dim3(32, 8, 2), blk256, 0, stream,
                       actC, w2t, nullptr, nullptr, pc, nullptr, nullptr,
                       1024, 2048, 4096, 4096, (long)4096 * 1024, 0);
    // final_raw = pc0+pc1 + b2 + pe -> f2 (+partials, chunks=64)
    hipLaunchKernelGGL(reduce2_res, gApply, blk256, 0, stream, pc, f0, b2, f2, partial);
    hipLaunchKernelGGL(transpose_dual, gT, blkT, 0, stream, f2, out, nullptr, S_, D_, partial, 64);

    (void)in_sizes; (void)n_in; (void)out_size; (void)ws_size;
}

// Round 8
// 514.244 us; speedup vs baseline: 1.1328x; 1.0403x over previous
//
#include <hip/hip_runtime.h>
#include <cmath>

#define B_   4
#define D_   1024
#define S_   1024
#define H_   16
#define DH_  64
#define DFF_ 4096

typedef __attribute__((ext_vector_type(8))) short bf16x8;  // 8 bf16 in 4 VGPRs
typedef __attribute__((ext_vector_type(4))) float f32x4;

__device__ __forceinline__ unsigned short f2b(float f) {
    unsigned int u = __float_as_uint(f);
    u += 0x7fffu + ((u >> 16) & 1u);   // RNE
    return (unsigned short)(u >> 16);
}

// async global->LDS, 16B per lane; LDS dest = wave-uniform base + lane*16
__device__ __forceinline__ void gload_lds16(const unsigned short* g, unsigned short* l) {
    __builtin_amdgcn_global_load_lds(
        (const __attribute__((address_space(1))) void*)g,
        (__attribute__((address_space(3))) void*)l, 16, 0, 0);
}

// ---------------------------------------------------------------------------
// bf16 MFMA GEMM, BMxBN tile, BK=64, 256 thr = 4 waves (2x2), wave tile
// (BM/2)x(BN/2) = 32 MFMAs per barrier pair. Grid (Mtiles, Ntiles, ksplit):
// x = M-tile so round-robin XCD (%8) clusters A row-tile sharers per XCD.
// LDS swizzle: staging lane fetches global 16B-chunk (lane&7)^(lane>>3) so
// LDS[r][c] holds global chunk c^(r&7); fragment reads un-permute. Bank
// spread = exactly 2-way (free) instead of 16-way at 128B row stride.
// RES fuses bias+residual+fp32-out+(sum,sumsq) partials for the next norm.
// ---------------------------------------------------------------------------
template <int BM, int BN, bool RES>
__global__ __launch_bounds__(256, 2)
void gemm_t(const unsigned short* __restrict__ A,   // [M,lda] bf16
            const unsigned short* __restrict__ Wt,  // [N,ldb] bf16
            const float* __restrict__ bias,
            const float* __restrict__ residual,     // RES: [M,N] fp32
            float* __restrict__ Cf, unsigned short* __restrict__ Cb,
            float* __restrict__ partial,            // RES: [B][chunks][2]
            int N, int K, int lda, int ldb, long csplit, int relu)
{
    constexpr int FM = BM / 32, FN = BN / 32;  // frags per wave
    __shared__ unsigned short As[BM * 64];
    __shared__ unsigned short Bs[BN * 64];
    const int tid = threadIdx.x;
    const int w = tid >> 6, lane = tid & 63;
    const int quad = lane >> 4, l16 = lane & 15;
    const int m0 = blockIdx.x * BM, n0 = blockIdx.y * BN;   // x = M-tile!
    const int wm = (w >> 1) * (BM / 2), wn = (w & 1) * (BN / 2);
    // staging: one inst = 64 lanes x 16B = 8 rows x 128B (8 chunks of 16B)
    const int srow = lane >> 3;                 // row within 8-row group
    const int scol = ((lane & 7) ^ srow) * 8;   // swizzled source chunk

    A  += (size_t)blockIdx.z * K;
    Wt += (size_t)blockIdx.z * K;
    if (Cf) Cf += (size_t)blockIdx.z * csplit;

    f32x4 acc[FM][FN] = {};

    for (int k0 = 0; k0 < K; k0 += 64) {
#pragma unroll
        for (int i = 0; i < BM / 32; ++i) {
            const int inst = w + 4 * i;
            gload_lds16(A + (size_t)(m0 + inst * 8 + srow) * lda + k0 + scol,
                        As + inst * 512);
        }
#pragma unroll
        for (int i = 0; i < BN / 32; ++i) {
            const int inst = w + 4 * i;
            gload_lds16(Wt + (size_t)(n0 + inst * 8 + srow) * ldb + k0 + scol,
                        Bs + inst * 512);
        }
        __syncthreads();

#pragma unroll
        for (int kk = 0; kk < 2; ++kk) {
            bf16x8 af[FM], bfr[FN];
#pragma unroll
            for (int i = 0; i < FM; ++i) {
                const int r = wm + i * 16 + l16;
                af[i] = *(const bf16x8*)&As[r * 64 + (((kk * 4 + quad) ^ (r & 7)) * 8)];
            }
#pragma unroll
            for (int j = 0; j < FN; ++j) {
                const int r = wn + j * 16 + l16;
                bfr[j] = *(const bf16x8*)&Bs[r * 64 + (((kk * 4 + quad) ^ (r & 7)) * 8)];
            }
#pragma unroll
            for (int i = 0; i < FM; ++i)
#pragma unroll
                for (int j = 0; j < FN; ++j)
                    acc[i][j] = __builtin_amdgcn_mfma_f32_16x16x32_bf16(af[i], bfr[j], acc[i][j], 0, 0, 0);
        }
        __syncthreads();
    }

    float s = 0.f, ss = 0.f;
#pragma unroll
    for (int i = 0; i < FM; ++i) {
        const int grow = m0 + wm + i * 16 + quad * 4;
#pragma unroll
        for (int j = 0; j < FN; ++j) {
            const int gcol = n0 + wn + j * 16 + l16;
            const float bv = bias ? bias[gcol] : 0.f;
#pragma unroll
            for (int r = 0; r < 4; ++r) {
                float vv = acc[i][j][r] + bv;
                if (relu) vv = fmaxf(vv, 0.f);
                if constexpr (RES) {
                    vv += residual[(size_t)(grow + r) * N + gcol];
                    s += vv; ss += vv * vv;
                    Cf[(size_t)(grow + r) * N + gcol] = vv;
                } else {
                    if (Cf) Cf[(size_t)(grow + r) * N + gcol] = vv;
                    if (Cb) Cb[(size_t)(grow + r) * N + gcol] = f2b(vv);
                }
            }
        }
    }

    if constexpr (RES) {
        float* rs = (float*)As;          // LDS reuse after final barrier
        float* rss = rs + 256;
        rs[tid] = s; rss[tid] = ss;
        __syncthreads();
        for (int off = 128; off > 0; off >>= 1) {
            if (tid < off) { rs[tid] += rs[tid + off]; rss[tid] += rss[tid + off]; }
            __syncthreads();
        }
        if (tid == 0) {
            constexpr int YPB = S_ / BM;                 // m-blocks per batch
            const int b = blockIdx.x / YPB;
            const int chunk = (blockIdx.x % YPB) * gridDim.y + blockIdx.y;
            const int chunks = YPB * gridDim.y;
            partial[((size_t)b * chunks + chunk) * 2 + 0] = rs[0];
            partial[((size_t)b * chunks + chunk) * 2 + 1] = rss[0];
        }
    }
}

// ---------------------------------------------------------------------------
// y = pc0+pc1 + bias[col] + res, with (sum,sumsq) partials. grid (64, B).
// ---------------------------------------------------------------------------
__global__ void reduce2_res(const float* __restrict__ pc, const float* __restrict__ res,
                            const float* __restrict__ bias, float* __restrict__ y,
                            float* __restrict__ partial)
{
    const size_t pcs = (size_t)4096 * 1024;
    const int b = blockIdx.y;
    const size_t base = (size_t)b * 1048576 + (size_t)blockIdx.x * 16384;
    float s = 0.f, ss = 0.f;
    for (int i = threadIdx.x; i < 4096; i += 256) {
        const size_t e = base + (size_t)i * 4;
        float4 v0 = *(const float4*)&pc[e];
        float4 v1 = *(const float4*)&pc[e + pcs];
        float4 rv = *(const float4*)&res[e];
        float4 bv = *(const float4*)&bias[e & 1023];
        float4 o;
        o.x = v0.x + v1.x + rv.x + bv.x;
        o.y = v0.y + v1.y + rv.y + bv.y;
        o.z = v0.z + v1.z + rv.z + bv.z;
        o.w = v0.w + v1.w + rv.w + bv.w;
        *(float4*)&y[e] = o;
        s += o.x + o.y + o.z + o.w;
        ss += o.x * o.x + o.y * o.y + o.z * o.z + o.w * o.w;
    }
    __shared__ float rs[256], rss[256];
    rs[threadIdx.x] = s; rss[threadIdx.x] = ss;
    __syncthreads();
    for (int off = 128; off > 0; off >>= 1) {
        if (threadIdx.x < off) {
            rs[threadIdx.x] += rs[threadIdx.x + off];
            rss[threadIdx.x] += rss[threadIdx.x + off];
        }
        __syncthreads();
    }
    if (threadIdx.x == 0) {
        partial[((size_t)b * 64 + blockIdx.x) * 2 + 0] = rs[0];
        partial[((size_t)b * 64 + blockIdx.x) * 2 + 1] = rss[0];
    }
}

// stats from partial: {mean, 1/(||x-mean||+eps)} computed in-block
__device__ __forceinline__ void stats_reduce(const float* __restrict__ partial,
                                             int b, int chunks, int tid,
                                             float* rs, float* rss,
                                             float& mean, float& inv)
{
    float s = 0.f, ss = 0.f;
    for (int i = tid; i < chunks; i += 256) {
        s  += partial[((size_t)b * chunks + i) * 2 + 0];
        ss += partial[((size_t)b * chunks + i) * 2 + 1];
    }
    rs[tid] = s; rss[tid] = ss;
    __syncthreads();
    for (int off = 128; off > 0; off >>= 1) {
        if (tid < off) { rs[tid] += rs[tid + off]; rss[tid] += rss[tid + off]; }
        __syncthreads();
    }
    const float size = (float)(D_ * S_);
    const float m = rs[0] / size;
    const float var = fmaxf(rss[0] - size * m * m, 0.f);
    mean = m;
    inv = 1.f / (sqrtf(var) + 1e-7f);
    __syncthreads();
}

// in-place normalize y (fp32) + write bf16 copy; stats inline. grid (64, B).
__global__ void norm_apply_dual(float* __restrict__ y, unsigned short* __restrict__ yb,
                                const float* __restrict__ partial, int chunks)
{
    __shared__ float rs[256], rss[256];
    const int b = blockIdx.y;
    float mean, inv;
    stats_reduce(partial, b, chunks, threadIdx.x, rs, rss, mean, inv);

    const int perBatch = D_ * S_;
    float4* y4 = (float4*)(y + (size_t)b * perBatch);
    unsigned short* yb_ = yb + (size_t)b * perBatch;
    const int n4 = perBatch / 4;
    for (int i = blockIdx.x * blockDim.x + threadIdx.x; i < n4;
         i += gridDim.x * blockDim.x) {
        float4 v = y4[i];
        v.x = (v.x - mean) * inv; v.y = (v.y - mean) * inv;
        v.z = (v.z - mean) * inv; v.w = (v.w - mean) * inv;
        y4[i] = v;
        ushort4 hh; hh.x = f2b(v.x); hh.y = f2b(v.y); hh.z = f2b(v.z); hh.w = f2b(v.w);
        *(ushort4*)(yb_ + (size_t)i * 4) = hh;
    }
}

// ---------------------------------------------------------------------------
// MFMA flash attention v2. grid (S/128, H, B), 256 thr = 4 waves; q-tile
// swizzled (qt = (bx+h)&7) so each XCD gets an even causal-diagonal mix.
// K staged [key][dh], V pre-transposed vt=[b,h,dh,S] -> Vt[dh][key]. No-max
// softmax (scores bounded), l reduced once at the end. P via LDS (C->A).
// ---------------------------------------------------------------------------
template <bool CAUSAL>
__global__ __launch_bounds__(256, 2)
void attn_mfma2(const unsigned short* __restrict__ q, const unsigned short* __restrict__ k,
                const unsigned short* __restrict__ vt, unsigned short* __restrict__ o,
                int qstride, int kstride)
{
    __shared__ unsigned short Ks[64][72];
    __shared__ unsigned short Vt[64][72];
    __shared__ unsigned short Ps[4][2][16][72];
    const int tid = threadIdx.x;
    const int w = tid >> 6, lane = tid & 63;
    const int quad = lane >> 4, l16 = lane & 15;
    const int h = blockIdx.y, b = blockIdx.z;
    const int qt = CAUSAL ? ((blockIdx.x + h) & 7) : blockIdx.x;
    const int q0 = qt * 128;

    const unsigned short* qA = q + (size_t)(b * S_ + q0 + w * 16 + l16) * qstride + h * DH_;
    const unsigned short* qB = qA + (size_t)64 * qstride;
    const bf16x8 qa0 = *(const bf16x8*)(qA + quad * 8);
    const bf16x8 qa1 = *(const bf16x8*)(qA + 32 + quad * 8);
    const bf16x8 qb0 = *(const bf16x8*)(qB + quad * 8);
    const bf16x8 qb1 = *(const bf16x8*)(qB + 32 + quad * 8);

    f32x4 OA[4] = {}, OB[4] = {};
    float lA[4] = {}, lB[4] = {};

    const int nblk = CAUSAL ? (2 * qt + 2) : (S_ / 64);
    for (int t = 0; t < nblk; ++t) {
        const int j0 = t * 64;
#pragma unroll
        for (int it = 0; it < 2; ++it) {
            const int id2 = tid + it * 256;
            const int row = id2 >> 3, c8 = (id2 & 7) * 8;
            *(bf16x8*)&Ks[row][c8] =
                *(const bf16x8*)(k + (size_t)(b * S_ + j0 + row) * kstride + h * DH_ + c8);
            *(bf16x8*)&Vt[row][c8] =
                *(const bf16x8*)(vt + (size_t)((b * H_ + h) * DH_ + row) * S_ + j0 + c8);
        }
        __syncthreads();

        const bool doA = !CAUSAL || (t <= 2 * qt);
        const bool diagA = CAUSAL && (t == 2 * qt);
        const bool diagB = CAUSAL && (t == 2 * qt + 1);

        f32x4 stA[4], stB[4];
#pragma unroll
        for (int n = 0; n < 4; ++n) {
            const bf16x8 kf0 = *(const bf16x8*)&Ks[n * 16 + l16][quad * 8];
            const bf16x8 kf1 = *(const bf16x8*)&Ks[n * 16 + l16][32 + quad * 8];
            if (doA) {
                f32x4 c = {};
                c = __builtin_amdgcn_mfma_f32_16x16x32_bf16(qa0, kf0, c, 0, 0, 0);
                c = __builtin_amdgcn_mfma_f32_16x16x32_bf16(qa1, kf1, c, 0, 0, 0);
                stA[n] = c;
            }
            f32x4 c = {};
            c = __builtin_amdgcn_mfma_f32_16x16x32_bf16(qb0, kf0, c, 0, 0, 0);
            c = __builtin_amdgcn_mfma_f32_16x16x32_bf16(qb1, kf1, c, 0, 0, 0);
            stB[n] = c;
        }

        if (doA) {
#pragma unroll
            for (int n = 0; n < 4; ++n)
#pragma unroll
                for (int r = 0; r < 4; ++r) {
                    float sv = stA[n][r] * 0.125f;
                    if (diagA) {
                        const int row = q0 + w * 16 + quad * 4 + r;
                        const int key = j0 + n * 16 + l16;
                        if (key > row) sv = -1e30f;
                    }
                    const float p = __expf(sv);
                    lA[r] += p;
                    Ps[w][0][quad * 4 + r][n * 16 + l16] = f2b(p);
                }
        }
#pragma unroll
        for (int n = 0; n < 4; ++n)
#pragma unroll
            for (int r = 0; r < 4; ++r) {
                float sv = stB[n][r] * 0.125f;
                if (diagB) {
                    const int row = q0 + 64 + w * 16 + quad * 4 + r;
                    const int key = j0 + n * 16 + l16;
                    if (key > row) sv = -1e30f;
                }
                const float p = __expf(sv);
                lB[r] += p;
                Ps[w][1][quad * 4 + r][n * 16 + l16] = f2b(p);
            }
        __threadfence_block();

        const bf16x8 pa0 = *(const bf16x8*)&Ps[w][0][l16][quad * 8];
        const bf16x8 pa1 = *(const bf16x8*)&Ps[w][0][l16][32 + quad * 8];
        const bf16x8 pb0 = *(const bf16x8*)&Ps[w][1][l16][quad * 8];
        const bf16x8 pb1 = *(const bf16x8*)&Ps[w][1][l16][32 + quad * 8];
#pragma unroll
        for (int n = 0; n < 4; ++n) {
            const bf16x8 vf0 = *(const bf16x8*)&Vt[n * 16 + l16][quad * 8];
            const bf16x8 vf1 = *(const bf16x8*)&Vt[n * 16 + l16][32 + quad * 8];
            if (doA) {
                OA[n] = __builtin_amdgcn_mfma_f32_16x16x32_bf16(pa0, vf0, OA[n], 0, 0, 0);
                OA[n] = __builtin_amdgcn_mfma_f32_16x16x32_bf16(pa1, vf1, OA[n], 0, 0, 0);
            }
            OB[n] = __builtin_amdgcn_mfma_f32_16x16x32_bf16(pb0, vf0, OB[n], 0, 0, 0);
            OB[n] = __builtin_amdgcn_mfma_f32_16x16x32_bf16(pb1, vf1, OB[n], 0, 0, 0);
        }
        __syncthreads();
    }

#pragma unroll
    for (int r = 0; r < 4; ++r) {
        float la = lA[r], lb = lB[r];
        la += __shfl_xor(la, 1); la += __shfl_xor(la, 2);
        la += __shfl_xor(la, 4); la += __shfl_xor(la, 8);
        lb += __shfl_xor(lb, 1); lb += __shfl_xor(lb, 2);
        lb += __shfl_xor(lb, 4); lb += __shfl_xor(lb, 8);
        const float ia = 1.f / la, ib = 1.f / lb;
        const size_t baseA = (size_t)(b * S_ + q0 + w * 16 + quad * 4 + r) * D_ + h * DH_;
        const size_t baseB = baseA + (size_t)64 * D_;
#pragma unroll
        for (int n = 0; n < 4; ++n) {
            o[baseA + n * 16 + l16] = f2b(OA[n][r] * ia);
            o[baseB + n * 16 + l16] = f2b(OB[n][r] * ib);
        }
    }
}

// ---------------------------------------------------------------------------
// u16 transpose for V: per (b,h) -> dst[((b*H+h)*64+dh)*S + s].
// grid (S/32, 2, B*H), block (32,8).
// ---------------------------------------------------------------------------
__global__ void transpose_v(const unsigned short* __restrict__ src,
                            unsigned short* __restrict__ dst, int istride)
{
    __shared__ unsigned short t[32][34];
    const int z = blockIdx.z, b = z >> 4, h = z & 15;
    const int s0 = blockIdx.x * 32, d0 = blockIdx.y * 32;
    const int tx = threadIdx.x, ty = threadIdx.y;
#pragma unroll
    for (int i = 0; i < 4; ++i)
        t[ty + i * 8][tx] =
            src[(size_t)(b * S_ + s0 + ty + i * 8) * istride + h * DH_ + d0 + tx];
    __syncthreads();
#pragma unroll
    for (int i = 0; i < 4; ++i)
        dst[(size_t)(z * DH_ + d0 + ty + i * 8) * S_ + s0 + tx] = t[tx][ty + i * 8];
}

// ---------------------------------------------------------------------------
// All weight transposes in one launch: 16 jobs of 1024x1024 fp32 -> bf16^T.
// grid (32,32,16), block (32,8).
// ---------------------------------------------------------------------------
struct WJob { const float* src; int sld; long doff; int dld; };
struct WJobs { WJob j[16]; };

__global__ void wtrans_all(WJobs js, unsigned short* __restrict__ dst)
{
    __shared__ float tile[32][33];
    const WJob J = js.j[blockIdx.z];
    const int c0 = blockIdx.x * 32, r0 = blockIdx.y * 32;
    const int tx = threadIdx.x, ty = threadIdx.y;
#pragma unroll
    for (int i = 0; i < 4; ++i)
        tile[ty + i * 8][tx] = J.src[(size_t)(r0 + ty + i * 8) * J.sld + c0 + tx];
    __syncthreads();
#pragma unroll
    for (int i = 0; i < 4; ++i)
        dst[J.doff + (size_t)(c0 + ty + i * 8) * J.dld + r0 + tx] =
            f2b(tile[tx][ty + i * 8]);
}

// ---------------------------------------------------------------------------
// Input transposes fused: z<4: other[b]^T -> f0 (fp32) + xb (bf16);
// z>=4: embedding[b]^T -> eb (bf16). grid (32,32,8), block (32,8).
// ---------------------------------------------------------------------------
__global__ void transpose_in(const float* __restrict__ other, const float* __restrict__ emb,
                             float* __restrict__ f0, unsigned short* __restrict__ xb,
                             unsigned short* __restrict__ eb)
{
    __shared__ float tile[32][33];
    const int z = blockIdx.z;
    const int b = z & 3;
    const bool isEmb = z >= 4;
    const float* ip = (isEmb ? emb : other) + (size_t)b * 1048576;
    const int c0 = blockIdx.x * 32, r0 = blockIdx.y * 32;
    const int tx = threadIdx.x, ty = threadIdx.y;
#pragma unroll
    for (int i = 0; i < 4; ++i)
        tile[ty + i * 8][tx] = ip[(size_t)(r0 + ty + i * 8) * 1024 + c0 + tx];
    __syncthreads();
#pragma unroll
    for (int i = 0; i < 4; ++i) {
        const float v = tile[tx][ty + i * 8];
        const size_t oidx = (size_t)b * 1048576 + (size_t)(c0 + ty + i * 8) * 1024 + r0 + tx;
        if (isEmb) eb[oidx] = f2b(v);
        else { f0[oidx] = v; xb[oidx] = f2b(v); }
    }
}

// ---------------------------------------------------------------------------
// Final: per-batch fp32 transpose with normalization (stats inline from
// partial). block (32,8), grid (32, 32, B).
// ---------------------------------------------------------------------------
__global__ void transpose_out(const float* __restrict__ in, float* __restrict__ outf,
                              const float* __restrict__ partial, int chunks)
{
    __shared__ float tile[32][33];
    __shared__ float rs[256], rss[256];
    const int z = blockIdx.z;
    const int tx = threadIdx.x, ty = threadIdx.y;
    const int tid = ty * 32 + tx;

    float mean, inv;
    stats_reduce(partial, z, chunks, tid, rs, rss, mean, inv);

    const float* ip = in + (size_t)z * 1048576;
    const int c0 = blockIdx.x * 32, r0 = blockIdx.y * 32;
#pragma unroll
    for (int i = 0; i < 4; ++i)
        tile[ty + i * 8][tx] = ip[(size_t)(r0 + ty + i * 8) * 1024 + c0 + tx];
    __syncthreads();
#pragma unroll
    for (int i = 0; i < 4; ++i) {
        const float v = (tile[tx][ty + i * 8] - mean) * inv;
        outf[(size_t)z * 1048576 + (size_t)(c0 + ty + i * 8) * 1024 + r0 + tx] = v;
    }
}

// ---------------------------------------------------------------------------
extern "C" void kernel_launch(void* const* d_in, const int* in_sizes, int n_in,
                              void* d_out, int out_size, void* d_ws, size_t ws_size,
                              hipStream_t stream)
{
    const float* embedding = (const float*)d_in[0];
    const float* other     = (const float*)d_in[1];
    const float* W1 = (const float*)d_in[10];
    const float* b1 = (const float*)d_in[11];
    const float* W2 = (const float*)d_in[12];
    const float* b2 = (const float*)d_in[13];
    float* out = (float*)d_out;

    char* wsb = (char*)d_ws;
    const size_t MB = 1u << 20;
    float* f0 = (float*)(wsb + 0 * MB);    // xT fp32 -> pe fp32
    float* f2 = (float*)(wsb + 16 * MB);   // pa fp32 -> final raw
    unsigned short* wts  = (unsigned short*)(wsb + 32 * MB);  // bf16 weights 32MB
    unsigned short* wqkv = wts;                       // [3072,1024]
    unsigned short* wo_s = wts + 3 * 1048576;
    unsigned short* wq_c = wts + 4 * 1048576;
    unsigned short* wkv_c= wts + 5 * 1048576;         // [2048,1024]
    unsigned short* wo_c = wts + 7 * 1048576;
    unsigned short* w1t  = wts + 8 * 1048576;         // [4096,1024]
    unsigned short* w2t  = wts + 12 * 1048576;        // [1024,4096]
    unsigned short* actA = (unsigned short*)(wsb + 64 * MB);  // 8MB (x_b16 / pa_b16 / vt)
    unsigned short* actB = (unsigned short*)(wsb + 72 * MB);  // 8MB (embT / vt_c)
    unsigned short* actC = (unsigned short*)(wsb + 80 * MB);  // 32MB (qkv / q+kv / h1 / attn-out)
    unsigned short* actC2 = actC + 4 * 1048576;
    unsigned short* aout  = actC + 12 * 1048576;      // attn output (8MB tail, ends at pc)
    float* pc      = (float*)(wsb + 112 * MB);        // 32MB: 2 K-split partials
    float* partial = (float*)(wsb + 176 * MB);

    const dim3 blkT(32, 8), blk256(256);
    const dim3 gAttn(S_ / 128, H_, B_);
    const dim3 gVt(32, 2, B_ * H_);
    const dim3 gApply(64, B_);

    // ---- weight prep: 8 squares + W1 (4 col-quarters) + W2 (4 row-quarters) ----
    WJobs js;
    for (int z = 0; z < 8; ++z)
        js.j[z] = { (const float*)d_in[2 + z], 1024, (long)z * 1048576, 1024 };
    for (int q = 0; q < 4; ++q)
        js.j[8 + q] = { W1 + (size_t)q * 1024, 4096, (long)(8 + q) * 1048576, 1024 };
    for (int q = 0; q < 4; ++q)
        js.j[12 + q] = { W2 + (size_t)q * 1048576, 1024, 12L * 1048576 + q * 1024, 4096 };
    hipLaunchKernelGGL(wtrans_all, dim3(32, 32, 16), blkT, 0, stream, js, wts);

    // ---- input transposes (both tensors, one launch) ----
    hipLaunchKernelGGL(transpose_in, dim3(32, 32, 8), blkT, 0, stream,
                       other, embedding, f0, actA, actB);

    // ---- self attention ----
    hipLaunchKernelGGL((gemm_t<128, 128, false>), dim3(32, 24), blk256, 0, stream,
                       actA, wqkv, nullptr, nullptr, nullptr, actC, nullptr,
                       3072, 1024, 1024, 1024, 0L, 0);
    hipLaunchKernelGGL(transpose_v, gVt, blkT, 0, stream, actC + 2048, actA, 3072);
    hipLaunchKernelGGL(attn_mfma2<true>, gAttn, blk256, 0, stream,
                       actC, actC + 1024, actA, aout, 3072, 3072);
    // pa_raw = attn@Wo_s + xT -> f2 (+partials, chunks=128)
    hipLaunchKernelGGL((gemm_t<64, 128, true>), dim3(64, 8), blk256, 0, stream,
                       aout, wo_s, nullptr, f0, f2, nullptr, partial,
                       1024, 1024, 1024, 1024, 0L, 0);
    hipLaunchKernelGGL(norm_apply_dual, gApply, blk256, 0, stream, f2, actA, partial, 128);

    // ---- cross attention (embT already in actB) ----
    hipLaunchKernelGGL((gemm_t<64, 128, false>), dim3(64, 8), blk256, 0, stream,
                       actA, wq_c, nullptr, nullptr, nullptr, actC, nullptr,
                       1024, 1024, 1024, 1024, 0L, 0);
    hipLaunchKernelGGL((gemm_t<128, 128, false>), dim3(32, 16), blk256, 0, stream,
                       actB, wkv_c, nullptr, nullptr, nullptr, actC2, nullptr,
                       2048, 1024, 1024, 1024, 0L, 0);
    hipLaunchKernelGGL(transpose_v, gVt, blkT, 0, stream, actC2 + 1024, actB, 2048);
    hipLaunchKernelGGL(attn_mfma2<false>, gAttn, blk256, 0, stream,
                       actC, actC2, actB, aout, 1024, 2048);
    // pe_raw = ca@Wo_c + pa -> f0 (+partials)
    hipLaunchKernelGGL((gemm_t<64, 128, true>), dim3(64, 8), blk256, 0, stream,
                       aout, wo_c, nullptr, f2, f0, nullptr, partial,
                       1024, 1024, 1024, 1024, 0L, 0);
    hipLaunchKernelGGL(norm_apply_dual, gApply, blk256, 0, stream, f0, actA, partial, 128);

    // ---- MLP ----
    hipLaunchKernelGGL((gemm_t<128, 128, false>), dim3(32, 32), blk256, 0, stream,
                       actA, w1t, b1, nullptr, nullptr, actC, nullptr,
                       DFF_, 1024, 1024, 1024, 0L, 1);
    // W2 K-split x2: pc[z] = h1[:, z*2048:(z+1)*2048] @ W2t[:, z*2048:...]^T
    hipLaunchKernelGGL((gemm_t<128, 128, false>), dim3(32, 8, 2), blk256, 0, stream,
                       actC, w2t, nullptr, nullptr, pc, nullptr, nullptr,
                       1024, 2048, 4096, 4096, (long)4096 * 1024, 0);
    // final_raw = pc0+pc1 + b2 + pe -> f2 (+partials, chunks=64)
    hipLaunchKernelGGL(reduce2_res, gApply, blk256, 0, stream, pc, f0, b2, f2, partial);
    hipLaunchKernelGGL(transpose_out, dim3(32, 32, B_), blkT, 0, stream, f2, out, partial, 64);

    (void)in_sizes; (void)n_in; (void)out_size; (void)ws_size;
}

// Round 9
// 500.927 us; speedup vs baseline: 1.1629x; 1.0266x over previous
//
#include <hip/hip_runtime.h>
#include <cmath>

#define B_   4
#define D_   1024
#define S_   1024
#define H_   16
#define DH_  64
#define DFF_ 4096

typedef __attribute__((ext_vector_type(8))) short bf16x8;  // 8 bf16 in 4 VGPRs
typedef __attribute__((ext_vector_type(4))) float f32x4;

__device__ __forceinline__ unsigned short f2b(float f) {
    unsigned int u = __float_as_uint(f);
    u += 0x7fffu + ((u >> 16) & 1u);   // RNE
    return (unsigned short)(u >> 16);
}

// async global->LDS, 16B per lane; LDS dest = wave-uniform base + lane*16
__device__ __forceinline__ void gload_lds16(const unsigned short* g, unsigned short* l) {
    __builtin_amdgcn_global_load_lds(
        (const __attribute__((address_space(1))) void*)g,
        (__attribute__((address_space(3))) void*)l, 16, 0, 0);
}

// ---------------------------------------------------------------------------
// bf16 MFMA GEMM, BMxBN tile, BK=64, 256 thr = 4 waves (2x2), wave tile
// (BM/2)x(BN/2) = 32 MFMAs per barrier pair. Grid (Mtiles, Ntiles, ksplit):
// x = M-tile so round-robin XCD (%8) clusters A row-tile sharers per XCD.
// LDS swizzle: staging lane fetches global 16B-chunk (lane&7)^(lane>>3) so
// LDS[r][c] holds global chunk c^(r&7); fragment reads un-permute. Bank
// spread = exactly 2-way (free) instead of 16-way at 128B row stride.
// RES fuses bias+residual+fp32-out+(sum,sumsq) partials for the next norm.
// ---------------------------------------------------------------------------
template <int BM, int BN, bool RES>
__global__ __launch_bounds__(256, 2)
void gemm_t(const unsigned short* __restrict__ A,   // [M,lda] bf16
            const unsigned short* __restrict__ Wt,  // [N,ldb] bf16
            const float* __restrict__ bias,
            const float* __restrict__ residual,     // RES: [M,N] fp32
            float* __restrict__ Cf, unsigned short* __restrict__ Cb,
            float* __restrict__ partial,            // RES: [B][chunks][2]
            int N, int K, int lda, int ldb, long csplit, int relu)
{
    constexpr int FM = BM / 32, FN = BN / 32;  // frags per wave
    __shared__ unsigned short As[BM * 64];
    __shared__ unsigned short Bs[BN * 64];
    const int tid = threadIdx.x;
    const int w = tid >> 6, lane = tid & 63;
    const int quad = lane >> 4, l16 = lane & 15;
    const int m0 = blockIdx.x * BM, n0 = blockIdx.y * BN;   // x = M-tile!
    const int wm = (w >> 1) * (BM / 2), wn = (w & 1) * (BN / 2);
    // staging: one inst = 64 lanes x 16B = 8 rows x 128B (8 chunks of 16B)
    const int srow = lane >> 3;                 // row within 8-row group
    const int scol = ((lane & 7) ^ srow) * 8;   // swizzled source chunk

    A  += (size_t)blockIdx.z * K;
    Wt += (size_t)blockIdx.z * K;
    if (Cf) Cf += (size_t)blockIdx.z * csplit;

    f32x4 acc[FM][FN] = {};

    for (int k0 = 0; k0 < K; k0 += 64) {
#pragma unroll
        for (int i = 0; i < BM / 32; ++i) {
            const int inst = w + 4 * i;
            gload_lds16(A + (size_t)(m0 + inst * 8 + srow) * lda + k0 + scol,
                        As + inst * 512);
        }
#pragma unroll
        for (int i = 0; i < BN / 32; ++i) {
            const int inst = w + 4 * i;
            gload_lds16(Wt + (size_t)(n0 + inst * 8 + srow) * ldb + k0 + scol,
                        Bs + inst * 512);
        }
        __syncthreads();

#pragma unroll
        for (int kk = 0; kk < 2; ++kk) {
            bf16x8 af[FM], bfr[FN];
#pragma unroll
            for (int i = 0; i < FM; ++i) {
                const int r = wm + i * 16 + l16;
                af[i] = *(const bf16x8*)&As[r * 64 + (((kk * 4 + quad) ^ (r & 7)) * 8)];
            }
#pragma unroll
            for (int j = 0; j < FN; ++j) {
                const int r = wn + j * 16 + l16;
                bfr[j] = *(const bf16x8*)&Bs[r * 64 + (((kk * 4 + quad) ^ (r & 7)) * 8)];
            }
#pragma unroll
            for (int i = 0; i < FM; ++i)
#pragma unroll
                for (int j = 0; j < FN; ++j)
                    acc[i][j] = __builtin_amdgcn_mfma_f32_16x16x32_bf16(af[i], bfr[j], acc[i][j], 0, 0, 0);
        }
        __syncthreads();
    }

    float s = 0.f, ss = 0.f;
#pragma unroll
    for (int i = 0; i < FM; ++i) {
        const int grow = m0 + wm + i * 16 + quad * 4;
#pragma unroll
        for (int j = 0; j < FN; ++j) {
            const int gcol = n0 + wn + j * 16 + l16;
            const float bv = bias ? bias[gcol] : 0.f;
#pragma unroll
            for (int r = 0; r < 4; ++r) {
                float vv = acc[i][j][r] + bv;
                if (relu) vv = fmaxf(vv, 0.f);
                if constexpr (RES) {
                    vv += residual[(size_t)(grow + r) * N + gcol];
                    s += vv; ss += vv * vv;
                    Cf[(size_t)(grow + r) * N + gcol] = vv;
                } else {
                    if (Cf) Cf[(size_t)(grow + r) * N + gcol] = vv;
                    if (Cb) Cb[(size_t)(grow + r) * N + gcol] = f2b(vv);
                }
            }
        }
    }

    if constexpr (RES) {
        float* rs = (float*)As;          // LDS reuse after final barrier
        float* rss = rs + 256;
        rs[tid] = s; rss[tid] = ss;
        __syncthreads();
        for (int off = 128; off > 0; off >>= 1) {
            if (tid < off) { rs[tid] += rs[tid + off]; rss[tid] += rss[tid + off]; }
            __syncthreads();
        }
        if (tid == 0) {
            constexpr int YPB = S_ / BM;                 // m-blocks per batch
            const int b = blockIdx.x / YPB;
            const int chunk = (blockIdx.x % YPB) * gridDim.y + blockIdx.y;
            const int chunks = YPB * gridDim.y;
            partial[((size_t)b * chunks + chunk) * 2 + 0] = rs[0];
            partial[((size_t)b * chunks + chunk) * 2 + 1] = rss[0];
        }
    }
}

// ---------------------------------------------------------------------------
// y = pc0+pc1 + bias[col] + res, with (sum,sumsq) partials. grid (64, B).
// ---------------------------------------------------------------------------
__global__ void reduce2_res(const float* __restrict__ pc, const float* __restrict__ res,
                            const float* __restrict__ bias, float* __restrict__ y,
                            float* __restrict__ partial)
{
    const size_t pcs = (size_t)4096 * 1024;
    const int b = blockIdx.y;
    const size_t base = (size_t)b * 1048576 + (size_t)blockIdx.x * 16384;
    float s = 0.f, ss = 0.f;
    for (int i = threadIdx.x; i < 4096; i += 256) {
        const size_t e = base + (size_t)i * 4;
        float4 v0 = *(const float4*)&pc[e];
        float4 v1 = *(const float4*)&pc[e + pcs];
        float4 rv = *(const float4*)&res[e];
        float4 bv = *(const float4*)&bias[e & 1023];
        float4 o;
        o.x = v0.x + v1.x + rv.x + bv.x;
        o.y = v0.y + v1.y + rv.y + bv.y;
        o.z = v0.z + v1.z + rv.z + bv.z;
        o.w = v0.w + v1.w + rv.w + bv.w;
        *(float4*)&y[e] = o;
        s += o.x + o.y + o.z + o.w;
        ss += o.x * o.x + o.y * o.y + o.z * o.z + o.w * o.w;
    }
    __shared__ float rs[256], rss[256];
    rs[threadIdx.x] = s; rss[threadIdx.x] = ss;
    __syncthreads();
    for (int off = 128; off > 0; off >>= 1) {
        if (threadIdx.x < off) {
            rs[threadIdx.x] += rs[threadIdx.x + off];
            rss[threadIdx.x] += rss[threadIdx.x + off];
        }
        __syncthreads();
    }
    if (threadIdx.x == 0) {
        partial[((size_t)b * 64 + blockIdx.x) * 2 + 0] = rs[0];
        partial[((size_t)b * 64 + blockIdx.x) * 2 + 1] = rss[0];
    }
}

// stats from partial: {mean, 1/(||x-mean||+eps)} computed in-block
__device__ __forceinline__ void stats_reduce(const float* __restrict__ partial,
                                             int b, int chunks, int tid,
                                             float* rs, float* rss,
                                             float& mean, float& inv)
{
    float s = 0.f, ss = 0.f;
    for (int i = tid; i < chunks; i += 256) {
        s  += partial[((size_t)b * chunks + i) * 2 + 0];
        ss += partial[((size_t)b * chunks + i) * 2 + 1];
    }
    rs[tid] = s; rss[tid] = ss;
    __syncthreads();
    for (int off = 128; off > 0; off >>= 1) {
        if (tid < off) { rs[tid] += rs[tid + off]; rss[tid] += rss[tid + off]; }
        __syncthreads();
    }
    const float size = (float)(D_ * S_);
    const float m = rs[0] / size;
    const float var = fmaxf(rss[0] - size * m * m, 0.f);
    mean = m;
    inv = 1.f / (sqrtf(var) + 1e-7f);
    __syncthreads();
}

// in-place normalize y (fp32) + write bf16 copy; stats inline. grid (64, B).
__global__ void norm_apply_dual(float* __restrict__ y, unsigned short* __restrict__ yb,
                                const float* __restrict__ partial, int chunks)
{
    __shared__ float rs[256], rss[256];
    const int b = blockIdx.y;
    float mean, inv;
    stats_reduce(partial, b, chunks, threadIdx.x, rs, rss, mean, inv);

    const int perBatch = D_ * S_;
    float4* y4 = (float4*)(y + (size_t)b * perBatch);
    unsigned short* yb_ = yb + (size_t)b * perBatch;
    const int n4 = perBatch / 4;
    for (int i = blockIdx.x * blockDim.x + threadIdx.x; i < n4;
         i += gridDim.x * blockDim.x) {
        float4 v = y4[i];
        v.x = (v.x - mean) * inv; v.y = (v.y - mean) * inv;
        v.z = (v.z - mean) * inv; v.w = (v.w - mean) * inv;
        y4[i] = v;
        ushort4 hh; hh.x = f2b(v.x); hh.y = f2b(v.y); hh.z = f2b(v.z); hh.w = f2b(v.w);
        *(ushort4*)(yb_ + (size_t)i * 4) = hh;
    }
}

// ---------------------------------------------------------------------------
// MFMA flash attention v3. grid (S/128, H, B), 256 thr = 4 waves; q-tile
// swizzled (qt = (bx+h)&7) so each XCD gets an even causal-diagonal mix.
// 128-key tiles staged per barrier pair via global_load_lds (async DMA):
// Ks [key][dh] with chunk ^= key&7 swizzle; Vt [dh][key] (pre-transposed
// vt=[b,h,dh,S] in global) with chunk ^= dh&15 swizzle — unpadded, DMA-
// contiguous dest, reads land at 2-way bank aliasing (free). No-max softmax
// (scores bounded), l reduced once at the end. P via LDS (C->A layout).
// ---------------------------------------------------------------------------
template <bool CAUSAL>
__global__ __launch_bounds__(256, 2)
void attn_mfma3(const unsigned short* __restrict__ q, const unsigned short* __restrict__ k,
                const unsigned short* __restrict__ vt, unsigned short* __restrict__ o,
                int qstride, int kstride)
{
    __shared__ unsigned short Ks[128 * 64];     // 16 KB, [key][dh] swizzled
    __shared__ unsigned short Vt[64 * 128];     // 16 KB, [dh][key] swizzled
    __shared__ unsigned short Ps[4][2][16][72]; // 18 KB
    const int tid = threadIdx.x;
    const int w = tid >> 6, lane = tid & 63;
    const int quad = lane >> 4, l16 = lane & 15;
    const int h = blockIdx.y, b = blockIdx.z;
    const int qt = CAUSAL ? ((blockIdx.x + h) & 7) : blockIdx.x;
    const int q0 = qt * 128;

    // staging lane maps (per 1KB inst): K = 8 rows x 8 chunks; V = 4 rows x 16 chunks
    const int ksr = lane >> 3, ksc = ((lane & 7) ^ (lane >> 3)) * 8;
    const int vsr = lane >> 4, vsc = lane & 15;

    const unsigned short* qA = q + (size_t)(b * S_ + q0 + w * 16 + l16) * qstride + h * DH_;
    const unsigned short* qB = qA + (size_t)64 * qstride;
    const bf16x8 qa0 = *(const bf16x8*)(qA + quad * 8);
    const bf16x8 qa1 = *(const bf16x8*)(qA + 32 + quad * 8);
    const bf16x8 qb0 = *(const bf16x8*)(qB + quad * 8);
    const bf16x8 qb1 = *(const bf16x8*)(qB + 32 + quad * 8);

    f32x4 OA[4] = {}, OB[4] = {};
    float lA[4] = {}, lB[4] = {};

    const int nit = CAUSAL ? (qt + 1) : (S_ / 128);
    for (int t = 0; t < nit; ++t) {
        const int j0 = t * 128;
#pragma unroll
        for (int i = 0; i < 4; ++i) {
            const int ins = w + 4 * i;
            gload_lds16(k + (size_t)(b * S_ + j0 + ins * 8 + ksr) * kstride + h * DH_ + ksc,
                        Ks + ins * 512);
            const int vrow = ins * 4 + vsr;
            gload_lds16(vt + (size_t)((b * H_ + h) * DH_ + vrow) * S_ + j0
                           + ((vsc ^ (vrow & 15)) * 8),
                        Vt + ins * 512);
        }
        __syncthreads();

#pragma unroll
        for (int g = 0; g < 2; ++g) {
            const int kb = 2 * t + g;
            const int jg = j0 + g * 64;
            const bool doA = !CAUSAL || (kb <= 2 * qt);
            const bool diagA = CAUSAL && (kb == 2 * qt);
            const bool diagB = CAUSAL && (kb == 2 * qt + 1);

            f32x4 stA[4], stB[4];
#pragma unroll
            for (int n = 0; n < 4; ++n) {
                const int kr = g * 64 + n * 16 + l16;
                const bf16x8 kf0 = *(const bf16x8*)&Ks[kr * 64 + ((quad ^ (kr & 7)) * 8)];
                const bf16x8 kf1 = *(const bf16x8*)&Ks[kr * 64 + (((quad + 4) ^ (kr & 7)) * 8)];
                if (doA) {
                    f32x4 c = {};
                    c = __builtin_amdgcn_mfma_f32_16x16x32_bf16(qa0, kf0, c, 0, 0, 0);
                    c = __builtin_amdgcn_mfma_f32_16x16x32_bf16(qa1, kf1, c, 0, 0, 0);
                    stA[n] = c;
                }
                f32x4 c = {};
                c = __builtin_amdgcn_mfma_f32_16x16x32_bf16(qb0, kf0, c, 0, 0, 0);
                c = __builtin_amdgcn_mfma_f32_16x16x32_bf16(qb1, kf1, c, 0, 0, 0);
                stB[n] = c;
            }

            if (doA) {
#pragma unroll
                for (int n = 0; n < 4; ++n)
#pragma unroll
                    for (int r = 0; r < 4; ++r) {
                        float sv = stA[n][r] * 0.125f;
                        if (diagA) {
                            const int row = q0 + w * 16 + quad * 4 + r;
                            const int key = jg + n * 16 + l16;
                            if (key > row) sv = -1e30f;
                        }
                        const float p = __expf(sv);
                        lA[r] += p;
                        Ps[w][0][quad * 4 + r][n * 16 + l16] = f2b(p);
                    }
            }
#pragma unroll
            for (int n = 0; n < 4; ++n)
#pragma unroll
                for (int r = 0; r < 4; ++r) {
                    float sv = stB[n][r] * 0.125f;
                    if (diagB) {
                        const int row = q0 + 64 + w * 16 + quad * 4 + r;
                        const int key = jg + n * 16 + l16;
                        if (key > row) sv = -1e30f;
                    }
                    const float p = __expf(sv);
                    lB[r] += p;
                    Ps[w][1][quad * 4 + r][n * 16 + l16] = f2b(p);
                }
            __threadfence_block();  // wave-local Ps write->read ordering

            const bf16x8 pa0 = *(const bf16x8*)&Ps[w][0][l16][quad * 8];
            const bf16x8 pa1 = *(const bf16x8*)&Ps[w][0][l16][32 + quad * 8];
            const bf16x8 pb0 = *(const bf16x8*)&Ps[w][1][l16][quad * 8];
            const bf16x8 pb1 = *(const bf16x8*)&Ps[w][1][l16][32 + quad * 8];
#pragma unroll
            for (int n = 0; n < 4; ++n) {
                const int vr = n * 16 + l16;
                const bf16x8 vf0 = *(const bf16x8*)&Vt[vr * 128 + (((g * 8 + quad) ^ l16) * 8)];
                const bf16x8 vf1 = *(const bf16x8*)&Vt[vr * 128 + (((g * 8 + quad + 4) ^ l16) * 8)];
                if (doA) {
                    OA[n] = __builtin_amdgcn_mfma_f32_16x16x32_bf16(pa0, vf0, OA[n], 0, 0, 0);
                    OA[n] = __builtin_amdgcn_mfma_f32_16x16x32_bf16(pa1, vf1, OA[n], 0, 0, 0);
                }
                OB[n] = __builtin_amdgcn_mfma_f32_16x16x32_bf16(pb0, vf0, OB[n], 0, 0, 0);
                OB[n] = __builtin_amdgcn_mfma_f32_16x16x32_bf16(pb1, vf1, OB[n], 0, 0, 0);
            }
        }
        __syncthreads();
    }

#pragma unroll
    for (int r = 0; r < 4; ++r) {
        float la = lA[r], lb = lB[r];
        la += __shfl_xor(la, 1); la += __shfl_xor(la, 2);
        la += __shfl_xor(la, 4); la += __shfl_xor(la, 8);
        lb += __shfl_xor(lb, 1); lb += __shfl_xor(lb, 2);
        lb += __shfl_xor(lb, 4); lb += __shfl_xor(lb, 8);
        const float ia = 1.f / la, ib = 1.f / lb;
        const size_t baseA = (size_t)(b * S_ + q0 + w * 16 + quad * 4 + r) * D_ + h * DH_;
        const size_t baseB = baseA + (size_t)64 * D_;
#pragma unroll
        for (int n = 0; n < 4; ++n) {
            o[baseA + n * 16 + l16] = f2b(OA[n][r] * ia);
            o[baseB + n * 16 + l16] = f2b(OB[n][r] * ib);
        }
    }
}

// ---------------------------------------------------------------------------
// u16 transpose for V: per (b,h) -> dst[((b*H+h)*64+dh)*S + s].
// grid (S/32, 2, B*H), block (32,8).
// ---------------------------------------------------------------------------
__global__ void transpose_v(const unsigned short* __restrict__ src,
                            unsigned short* __restrict__ dst, int istride)
{
    __shared__ unsigned short t[32][34];
    const int z = blockIdx.z, b = z >> 4, h = z & 15;
    const int s0 = blockIdx.x * 32, d0 = blockIdx.y * 32;
    const int tx = threadIdx.x, ty = threadIdx.y;
#pragma unroll
    for (int i = 0; i < 4; ++i)
        t[ty + i * 8][tx] =
            src[(size_t)(b * S_ + s0 + ty + i * 8) * istride + h * DH_ + d0 + tx];
    __syncthreads();
#pragma unroll
    for (int i = 0; i < 4; ++i)
        dst[(size_t)(z * DH_ + d0 + ty + i * 8) * S_ + s0 + tx] = t[tx][ty + i * 8];
}

// ---------------------------------------------------------------------------
// All weight transposes in one launch: 16 jobs of 1024x1024 fp32 -> bf16^T.
// grid (32,32,16), block (32,8).
// ---------------------------------------------------------------------------
struct WJob { const float* src; int sld; long doff; int dld; };
struct WJobs { WJob j[16]; };

__global__ void wtrans_all(WJobs js, unsigned short* __restrict__ dst)
{
    __shared__ float tile[32][33];
    const WJob J = js.j[blockIdx.z];
    const int c0 = blockIdx.x * 32, r0 = blockIdx.y * 32;
    const int tx = threadIdx.x, ty = threadIdx.y;
#pragma unroll
    for (int i = 0; i < 4; ++i)
        tile[ty + i * 8][tx] = J.src[(size_t)(r0 + ty + i * 8) * J.sld + c0 + tx];
    __syncthreads();
#pragma unroll
    for (int i = 0; i < 4; ++i)
        dst[J.doff + (size_t)(c0 + ty + i * 8) * J.dld + r0 + tx] =
            f2b(tile[tx][ty + i * 8]);
}

// ---------------------------------------------------------------------------
// Input transposes fused: z<4: other[b]^T -> f0 (fp32) + xb (bf16);
// z>=4: embedding[b]^T -> eb (bf16). grid (32,32,8), block (32,8).
// ---------------------------------------------------------------------------
__global__ void transpose_in(const float* __restrict__ other, const float* __restrict__ emb,
                             float* __restrict__ f0, unsigned short* __restrict__ xb,
                             unsigned short* __restrict__ eb)
{
    __shared__ float tile[32][33];
    const int z = blockIdx.z;
    const int b = z & 3;
    const bool isEmb = z >= 4;
    const float* ip = (isEmb ? emb : other) + (size_t)b * 1048576;
    const int c0 = blockIdx.x * 32, r0 = blockIdx.y * 32;
    const int tx = threadIdx.x, ty = threadIdx.y;
#pragma unroll
    for (int i = 0; i < 4; ++i)
        tile[ty + i * 8][tx] = ip[(size_t)(r0 + ty + i * 8) * 1024 + c0 + tx];
    __syncthreads();
#pragma unroll
    for (int i = 0; i < 4; ++i) {
        const float v = tile[tx][ty + i * 8];
        const size_t oidx = (size_t)b * 1048576 + (size_t)(c0 + ty + i * 8) * 1024 + r0 + tx;
        if (isEmb) eb[oidx] = f2b(v);
        else { f0[oidx] = v; xb[oidx] = f2b(v); }
    }
}

// ---------------------------------------------------------------------------
// Final: per-batch fp32 transpose with normalization (stats inline from
// partial). block (32,8), grid (32, 32, B).
// ---------------------------------------------------------------------------
__global__ void transpose_out(const float* __restrict__ in, float* __restrict__ outf,
                              const float* __restrict__ partial, int chunks)
{
    __shared__ float tile[32][33];
    __shared__ float rs[256], rss[256];
    const int z = blockIdx.z;
    const int tx = threadIdx.x, ty = threadIdx.y;
    const int tid = ty * 32 + tx;

    float mean, inv;
    stats_reduce(partial, z, chunks, tid, rs, rss, mean, inv);

    const float* ip = in + (size_t)z * 1048576;
    const int c0 = blockIdx.x * 32, r0 = blockIdx.y * 32;
#pragma unroll
    for (int i = 0; i < 4; ++i)
        tile[ty + i * 8][tx] = ip[(size_t)(r0 + ty + i * 8) * 1024 + c0 + tx];
    __syncthreads();
#pragma unroll
    for (int i = 0; i < 4; ++i) {
        const float v = (tile[tx][ty + i * 8] - mean) * inv;
        outf[(size_t)z * 1048576 + (size_t)(c0 + ty + i * 8) * 1024 + r0 + tx] = v;
    }
}

// ---------------------------------------------------------------------------
extern "C" void kernel_launch(void* const* d_in, const int* in_sizes, int n_in,
                              void* d_out, int out_size, void* d_ws, size_t ws_size,
                              hipStream_t stream)
{
    const float* embedding = (const float*)d_in[0];
    const float* other     = (const float*)d_in[1];
    const float* W1 = (const float*)d_in[10];
    const float* b1 = (const float*)d_in[11];
    const float* W2 = (const float*)d_in[12];
    const float* b2 = (const float*)d_in[13];
    float* out = (float*)d_out;

    char* wsb = (char*)d_ws;
    const size_t MB = 1u << 20;
    float* f0 = (float*)(wsb + 0 * MB);    // xT fp32 -> pe fp32
    float* f2 = (float*)(wsb + 16 * MB);   // pa fp32 -> final raw
    unsigned short* wts  = (unsigned short*)(wsb + 32 * MB);  // bf16 weights 32MB
    unsigned short* wqkv = wts;                       // [3072,1024]
    unsigned short* wo_s = wts + 3 * 1048576;
    unsigned short* wq_c = wts + 4 * 1048576;
    unsigned short* wkv_c= wts + 5 * 1048576;         // [2048,1024]
    unsigned short* wo_c = wts + 7 * 1048576;
    unsigned short* w1t  = wts + 8 * 1048576;         // [4096,1024]
    unsigned short* w2t  = wts + 12 * 1048576;        // [1024,4096]
    unsigned short* actA = (unsigned short*)(wsb + 64 * MB);  // 8MB (x_b16 / pa_b16 / vt)
    unsigned short* actB = (unsigned short*)(wsb + 72 * MB);  // 8MB (embT / vt_c)
    unsigned short* actC = (unsigned short*)(wsb + 80 * MB);  // 32MB (qkv / q+kv / h1)
    unsigned short* actC2 = actC + 4 * 1048576;
    unsigned short* aout  = actC + 12 * 1048576;      // attn output (8MB tail, ends at pc)
    float* pc      = (float*)(wsb + 112 * MB);        // 32MB: 2 K-split partials
    float* partial = (float*)(wsb + 176 * MB);

    const dim3 blkT(32, 8), blk256(256);
    const dim3 gAttn(S_ / 128, H_, B_);
    const dim3 gVt(32, 2, B_ * H_);
    const dim3 gApply(64, B_);

    // ---- weight prep: 8 squares + W1 (4 col-quarters) + W2 (4 row-quarters) ----
    WJobs js;
    for (int z = 0; z < 8; ++z)
        js.j[z] = { (const float*)d_in[2 + z], 1024, (long)z * 1048576, 1024 };
    for (int q = 0; q < 4; ++q)
        js.j[8 + q] = { W1 + (size_t)q * 1024, 4096, (long)(8 + q) * 1048576, 1024 };
    for (int q = 0; q < 4; ++q)
        js.j[12 + q] = { W2 + (size_t)q * 1048576, 1024, 12L * 1048576 + q * 1024, 4096 };
    hipLaunchKernelGGL(wtrans_all, dim3(32, 32, 16), blkT, 0, stream, js, wts);

    // ---- input transposes (both tensors, one launch) ----
    hipLaunchKernelGGL(transpose_in, dim3(32, 32, 8), blkT, 0, stream,
                       other, embedding, f0, actA, actB);

    // ---- self attention ----
    hipLaunchKernelGGL((gemm_t<128, 128, false>), dim3(32, 24), blk256, 0, stream,
                       actA, wqkv, nullptr, nullptr, nullptr, actC, nullptr,
                       3072, 1024, 1024, 1024, 0L, 0);
    hipLaunchKernelGGL(transpose_v, gVt, blkT, 0, stream, actC + 2048, actA, 3072);
    hipLaunchKernelGGL(attn_mfma3<true>, gAttn, blk256, 0, stream,
                       actC, actC + 1024, actA, aout, 3072, 3072);
    // pa_raw = attn@Wo_s + xT -> f2 (+partials, chunks=128)
    hipLaunchKernelGGL((gemm_t<64, 128, true>), dim3(64, 8), blk256, 0, stream,
                       aout, wo_s, nullptr, f0, f2, nullptr, partial,
                       1024, 1024, 1024, 1024, 0L, 0);
    hipLaunchKernelGGL(norm_apply_dual, gApply, blk256, 0, stream, f2, actA, partial, 128);

    // ---- cross attention (embT already in actB) ----
    hipLaunchKernelGGL((gemm_t<64, 128, false>), dim3(64, 8), blk256, 0, stream,
                       actA, wq_c, nullptr, nullptr, nullptr, actC, nullptr,
                       1024, 1024, 1024, 1024, 0L, 0);
    hipLaunchKernelGGL((gemm_t<128, 128, false>), dim3(32, 16), blk256, 0, stream,
                       actB, wkv_c, nullptr, nullptr, nullptr, actC2, nullptr,
                       2048, 1024, 1024, 1024, 0L, 0);
    hipLaunchKernelGGL(transpose_v, gVt, blkT, 0, stream, actC2 + 1024, actB, 2048);
    hipLaunchKernelGGL(attn_mfma3<false>, gAttn, blk256, 0, stream,
                       actC, actC2, actB, aout, 1024, 2048);
    // pe_raw = ca@Wo_c + pa -> f0 (+partials)
    hipLaunchKernelGGL((gemm_t<64, 128, true>), dim3(64, 8), blk256, 0, stream,
                       aout, wo_c, nullptr, f2, f0, nullptr, partial,
                       1024, 1024, 1024, 1024, 0L, 0);
    hipLaunchKernelGGL(norm_apply_dual, gApply, blk256, 0, stream, f0, actA, partial, 128);

    // ---- MLP ----
    hipLaunchKernelGGL((gemm_t<128, 128, false>), dim3(32, 32), blk256, 0, stream,
                       actA, w1t, b1, nullptr, nullptr, actC, nullptr,
                       DFF_, 1024, 1024, 1024, 0L, 1);
    // W2 K-split x2: pc[z] = h1[:, z*2048:(z+1)*2048] @ W2t[:, z*2048:...]^T
    hipLaunchKernelGGL((gemm_t<128, 128, false>), dim3(32, 8, 2), blk256, 0, stream,
                       actC, w2t, nullptr, nullptr, pc, nullptr, nullptr,
                       1024, 2048, 4096, 4096, (long)4096 * 1024, 0);
    // final_raw = pc0+pc1 + b2 + pe -> f2 (+partials, chunks=64)
    hipLaunchKernelGGL(reduce2_res, gApply, blk256, 0, stream, pc, f0, b2, f2, partial);
    hipLaunchKernelGGL(transpose_out, dim3(32, 32, B_), blkT, 0, stream, f2, out, partial, 64);

    (void)in_sizes; (void)n_in; (void)out_size; (void)ws_size;
}